// Round 1
// baseline (1602.757 us; speedup 1.0000x reference)
//
#include <hip/hip_runtime.h>
#include <hip/hip_bf16.h>

#define N_NODES 50000
#define N_EDGES 400000
#define IN_DIM 24
#define HID 256
#define OUT_DIM 12

// ---------------- Tiled linear: Y[N,M] = relu?(X[N,K] @ W[K,M] + b[M]) ----------------
template<int K, int M, int ROWS, bool RELU>
__global__ __launch_bounds__(M) void lin_tiled(const float* __restrict__ X,
                                               const float* __restrict__ W,
                                               const float* __restrict__ b,
                                               float* __restrict__ Y, int N) {
    __shared__ float xs[ROWS][K];
    const int row0 = blockIdx.x * ROWS;
    const int tid = threadIdx.x;
    for (int i = tid; i < ROWS * K; i += M) {
        int r = i / K, k = i - r * K;
        int gr = row0 + r;
        xs[r][k] = (gr < N) ? X[(long long)gr * K + k] : 0.f;
    }
    __syncthreads();
    const int j = tid;
    float acc[ROWS];
    float bj = b[j];
#pragma unroll
    for (int r = 0; r < ROWS; ++r) acc[r] = bj;
    for (int k = 0; k < K; ++k) {
        float w = W[k * M + j];
#pragma unroll
        for (int r = 0; r < ROWS; ++r) acc[r] = fmaf(xs[r][k], w, acc[r]);
    }
#pragma unroll
    for (int r = 0; r < ROWS; ++r) {
        int gr = row0 + r;
        if (gr < N) {
            float v = RELU ? fmaxf(acc[r], 0.f) : acc[r];
            Y[(long long)gr * M + j] = v;
        }
    }
}

// ---------------- Degree count ----------------
__global__ void count_kernel(const int* __restrict__ dst, float* __restrict__ cnt, int E) {
    int e = blockIdx.x * blockDim.x + threadIdx.x;
    if (e < E) atomicAdd(&cnt[dst[e]], 1.0f);
}

// ---------------- Edge scatter-add: agg[dst] += h[src], 256 channels ----------------
__global__ __launch_bounds__(256) void agg_kernel(const float* __restrict__ h,
                                                  const int* __restrict__ src,
                                                  const int* __restrict__ dst,
                                                  float* __restrict__ agg, int E) {
    int e = blockIdx.x;
    if (e >= E) return;
    int s = src[e];
    int d = dst[e];
    int c = threadIdx.x;
    atomicAdd(&agg[(long long)d * HID + c], h[(long long)s * HID + c]);
}

// ---------------- Fused SAGE linear: Y = relu(mean @ wl + bl + h @ wr) ----------------
template<int ROWS>
__global__ __launch_bounds__(HID) void sage_tiled(const float* __restrict__ agg,
                                                  const float* __restrict__ cnt,
                                                  const float* __restrict__ h,
                                                  const float* __restrict__ wl,
                                                  const float* __restrict__ bl,
                                                  const float* __restrict__ wr,
                                                  float* __restrict__ Y, int N) {
    __shared__ float ms[ROWS][HID];
    __shared__ float hs[ROWS][HID];
    const int row0 = blockIdx.x * ROWS;
    const int tid = threadIdx.x;
    for (int i = tid; i < ROWS * HID; i += HID) {
        int r = i >> 8, k = i & (HID - 1);
        int gr = row0 + r;
        if (gr < N) {
            float inv = 1.0f / fmaxf(cnt[gr], 1.0f);
            ms[r][k] = agg[(long long)gr * HID + k] * inv;
            hs[r][k] = h[(long long)gr * HID + k];
        } else {
            ms[r][k] = 0.f; hs[r][k] = 0.f;
        }
    }
    __syncthreads();
    const int j = tid;
    float acc[ROWS];
    float bj = bl[j];
#pragma unroll
    for (int r = 0; r < ROWS; ++r) acc[r] = bj;
    for (int k = 0; k < HID; ++k) {
        float wlv = wl[k * HID + j];
        float wrv = wr[k * HID + j];
#pragma unroll
        for (int r = 0; r < ROWS; ++r)
            acc[r] = fmaf(ms[r][k], wlv, fmaf(hs[r][k], wrv, acc[r]));
    }
#pragma unroll
    for (int r = 0; r < ROWS; ++r) {
        int gr = row0 + r;
        if (gr < N) Y[(long long)gr * HID + j] = fmaxf(acc[r], 0.f);
    }
}

// ---------------- Final linear: out[N,12] = h[N,128] @ W[128,12] + b ----------------
__global__ void lin_final(const float* __restrict__ X, const float* __restrict__ W,
                          const float* __restrict__ b, float* __restrict__ Y, int N) {
    int idx = blockIdx.x * blockDim.x + threadIdx.x;
    if (idx >= N * OUT_DIM) return;
    int row = idx / OUT_DIM;
    int j = idx - row * OUT_DIM;
    float acc = b[j];
#pragma unroll 8
    for (int k = 0; k < 128; ++k)
        acc = fmaf(X[row * 128 + k], W[k * OUT_DIM + j], acc);
    Y[idx] = acc;
}

extern "C" void kernel_launch(void* const* d_in, const int* in_sizes, int n_in,
                              void* d_out, int out_size, void* d_ws, size_t ws_size,
                              hipStream_t stream) {
    const float* x      = (const float*)d_in[0];
    const int*   eidx   = (const int*)d_in[1];
    const float* enc_w1 = (const float*)d_in[2];
    const float* enc_b1 = (const float*)d_in[3];
    const float* enc_w2 = (const float*)d_in[4];
    const float* enc_b2 = (const float*)d_in[5];
    const float* s1_wl  = (const float*)d_in[6];
    const float* s1_bl  = (const float*)d_in[7];
    const float* s1_wr  = (const float*)d_in[8];
    const float* s2_wl  = (const float*)d_in[9];
    const float* s2_bl  = (const float*)d_in[10];
    const float* s2_wr  = (const float*)d_in[11];
    const float* ro_w1  = (const float*)d_in[12];
    const float* ro_b1  = (const float*)d_in[13];
    const float* ro_w2  = (const float*)d_in[14];
    const float* ro_b2  = (const float*)d_in[15];
    float* out = (float*)d_out;

    const int N = N_NODES;
    const int E = N_EDGES;
    const int* src = eidx;
    const int* dst = eidx + E;

    // Workspace layout (f32)
    char* ws = (char*)d_ws;
    size_t off = 0;
    float* cnt  = (float*)(ws + off); off += ((size_t)N * 4 + 255) & ~255ULL;          // [N]
    float* buf0 = (float*)(ws + off); off += (size_t)N * 128 * 4;                       // [N,128]
    float* bufA = (float*)(ws + off); off += (size_t)N * HID * 4;                       // [N,256]
    float* bufB = (float*)(ws + off); off += (size_t)N * HID * 4;                       // [N,256]
    float* bufC = (float*)(ws + off); off += (size_t)N * HID * 4;                       // [N,256]

    const int ROWS = 8;
    const int nb = (N + ROWS - 1) / ROWS;

    // encoder
    lin_tiled<IN_DIM, 128, ROWS, true><<<nb, 128, 0, stream>>>(x, enc_w1, enc_b1, buf0, N);
    lin_tiled<128, HID, ROWS, true><<<nb, HID, 0, stream>>>(buf0, enc_w2, enc_b2, bufA, N);

    // degree counts (shared across both SAGE layers)
    hipMemsetAsync(cnt, 0, (size_t)N * 4, stream);
    count_kernel<<<(E + 255) / 256, 256, 0, stream>>>(dst, cnt, E);

    // SAGE layer 1: bufA -> bufC
    hipMemsetAsync(bufB, 0, (size_t)N * HID * 4, stream);
    agg_kernel<<<E, HID, 0, stream>>>(bufA, src, dst, bufB, E);
    sage_tiled<ROWS><<<nb, HID, 0, stream>>>(bufB, cnt, bufA, s1_wl, s1_bl, s1_wr, bufC, N);

    // SAGE layer 2: bufC -> bufA
    hipMemsetAsync(bufB, 0, (size_t)N * HID * 4, stream);
    agg_kernel<<<E, HID, 0, stream>>>(bufC, src, dst, bufB, E);
    sage_tiled<ROWS><<<nb, HID, 0, stream>>>(bufB, cnt, bufC, s2_wl, s2_bl, s2_wr, bufA, N);

    // readout
    lin_tiled<HID, 128, ROWS, true><<<nb, 128, 0, stream>>>(bufA, ro_w1, ro_b1, buf0, N);
    lin_final<<<(N * OUT_DIM + 255) / 256, 256, 0, stream>>>(buf0, ro_w2, ro_b2, out, N);
}

// Round 2
// 1278.726 us; speedup vs baseline: 1.2534x; 1.2534x over previous
//
#include <hip/hip_runtime.h>
#include <hip/hip_bf16.h>

#define N_NODES 50000
#define N_EDGES 400000
#define IN_DIM 24
#define HID 256
#define OUT_DIM 12

// ---------------- Small tiled linear for encoder layer 1 (K=24) ----------------
template<int K, int M, int ROWS, bool RELU>
__global__ __launch_bounds__(M) void lin_tiled(const float* __restrict__ X,
                                               const float* __restrict__ W,
                                               const float* __restrict__ b,
                                               float* __restrict__ Y, int N) {
    __shared__ float xs[ROWS][K];
    const int row0 = blockIdx.x * ROWS;
    const int tid = threadIdx.x;
    for (int i = tid; i < ROWS * K; i += M) {
        int r = i / K, k = i - r * K;
        int gr = row0 + r;
        xs[r][k] = (gr < N) ? X[(long long)gr * K + k] : 0.f;
    }
    __syncthreads();
    const int j = tid;
    float acc[ROWS];
    float bj = b[j];
#pragma unroll
    for (int r = 0; r < ROWS; ++r) acc[r] = bj;
    for (int k = 0; k < K; ++k) {
        float w = W[k * M + j];
#pragma unroll
        for (int r = 0; r < ROWS; ++r) acc[r] = fmaf(xs[r][k], w, acc[r]);
    }
#pragma unroll
    for (int r = 0; r < ROWS; ++r) {
        int gr = row0 + r;
        if (gr < N) {
            float v = RELU ? fmaxf(acc[r], 0.f) : acc[r];
            Y[(long long)gr * M + j] = v;
        }
    }
}

// ---------------- Register-tiled GEMM: Y[N,M] = relu?(X' @ W' + b) ----------------
// MODE 0: X' = X[N,K], W' = W[K,M]
// MODE 1 (SAGE, K=512): X' = concat(agg/max(cnt,1), h) [N,512], W' = [wl; wr]
// Block: 256 threads as 16x16; BM=128 rows, BN=128 cols, BK=32; 8x8 per thread.
template<int K, int M, int MODE, bool RELU>
__global__ __launch_bounds__(256) void gemm_rt(const float* __restrict__ A,
                                               const float* __restrict__ A2,
                                               const float* __restrict__ cnt,
                                               const float* __restrict__ W,
                                               const float* __restrict__ W2,
                                               const float* __restrict__ bias,
                                               float* __restrict__ Y, int N) {
    constexpr int BM = 128, BN = 128, BK = 32;
    __shared__ float xs[BM][BK + 4];
    __shared__ float ws[BK][BN + 4];
    const int tid = threadIdx.x;
    const int tx = tid & 15, ty = tid >> 4;
    const int r0 = blockIdx.x * BM;
    const int j0 = blockIdx.y * BN;

    float acc[8][8];
#pragma unroll
    for (int u = 0; u < 8; ++u) {
        float b = bias[j0 + tx + 16 * u];
#pragma unroll
        for (int v = 0; v < 8; ++v) acc[v][u] = b;
    }

    const int srow = tid >> 1;            // 0..127
    const int scol = (tid & 1) * 16;      // 0 or 16
    const int wrow = tid >> 3;            // 0..31
    const int wcol = (tid & 7) * 16;      // 0..112

    for (int kc = 0; kc < K; kc += BK) {
        // ---- stage X tile (BM x BK) ----
        {
            int gr = r0 + srow;
            float4 v0, v1, v2, v3;
            if (gr < N) {
                const float* p;
                float scale = 1.0f;
                int kg = kc + scol;
                if (MODE == 1) {
                    if (kg < HID) {
                        p = A + (long long)gr * HID + kg;
                        scale = 1.0f / fmaxf(cnt[gr], 1.0f);
                    } else {
                        p = A2 + (long long)gr * HID + (kg - HID);
                    }
                } else {
                    p = A + (long long)gr * K + kg;
                }
                v0 = ((const float4*)p)[0];
                v1 = ((const float4*)p)[1];
                v2 = ((const float4*)p)[2];
                v3 = ((const float4*)p)[3];
                if (MODE == 1) {
                    v0.x *= scale; v0.y *= scale; v0.z *= scale; v0.w *= scale;
                    v1.x *= scale; v1.y *= scale; v1.z *= scale; v1.w *= scale;
                    v2.x *= scale; v2.y *= scale; v2.z *= scale; v2.w *= scale;
                    v3.x *= scale; v3.y *= scale; v3.z *= scale; v3.w *= scale;
                }
            } else {
                v0 = v1 = v2 = v3 = make_float4(0.f, 0.f, 0.f, 0.f);
            }
            float* q = &xs[srow][scol];
            ((float4*)q)[0] = v0; ((float4*)q)[1] = v1;
            ((float4*)q)[2] = v2; ((float4*)q)[3] = v3;
        }
        // ---- stage W tile (BK x BN) ----
        {
            int kg = kc + wrow;
            const float* wp;
            if (MODE == 1) {
                wp = (kg < HID) ? (W + (long long)kg * M + j0 + wcol)
                                : (W2 + (long long)(kg - HID) * M + j0 + wcol);
            } else {
                wp = W + (long long)kg * M + j0 + wcol;
            }
            float4 w0 = ((const float4*)wp)[0];
            float4 w1 = ((const float4*)wp)[1];
            float4 w2 = ((const float4*)wp)[2];
            float4 w3 = ((const float4*)wp)[3];
            float* q = &ws[wrow][wcol];
            ((float4*)q)[0] = w0; ((float4*)q)[1] = w1;
            ((float4*)q)[2] = w2; ((float4*)q)[3] = w3;
        }
        __syncthreads();
#pragma unroll 8
        for (int kk = 0; kk < BK; ++kk) {
            float xv[8], wv[8];
#pragma unroll
            for (int v = 0; v < 8; ++v) xv[v] = xs[ty + 16 * v][kk];
#pragma unroll
            for (int u = 0; u < 8; ++u) wv[u] = ws[kk][tx + 16 * u];
#pragma unroll
            for (int v = 0; v < 8; ++v)
#pragma unroll
                for (int u = 0; u < 8; ++u)
                    acc[v][u] = fmaf(xv[v], wv[u], acc[v][u]);
        }
        __syncthreads();
    }

    // ---- epilogue ----
#pragma unroll
    for (int v = 0; v < 8; ++v) {
        int gr = r0 + ty + 16 * v;
        if (gr < N) {
#pragma unroll
            for (int u = 0; u < 8; ++u) {
                float val = acc[v][u];
                if (RELU) val = fmaxf(val, 0.f);
                Y[(long long)gr * M + j0 + tx + 16 * u] = val;
            }
        }
    }
}

// ---------------- Degree count ----------------
__global__ void count_kernel(const int* __restrict__ dst, float* __restrict__ cnt, int E) {
    int e = blockIdx.x * blockDim.x + threadIdx.x;
    if (e < E) atomicAdd(&cnt[dst[e]], 1.0f);
}

// ---------------- Edge scatter-add: agg[dst] += h[src], 256 channels ----------------
__global__ __launch_bounds__(256) void agg_kernel(const float* __restrict__ h,
                                                  const int* __restrict__ src,
                                                  const int* __restrict__ dst,
                                                  float* __restrict__ agg, int E) {
    int e = blockIdx.x;
    if (e >= E) return;
    int s = src[e];
    int d = dst[e];
    int c = threadIdx.x;
    atomicAdd(&agg[(long long)d * HID + c], h[(long long)s * HID + c]);
}

// ---------------- Final linear: out[N,12] = h[N,128] @ W[128,12] + b ----------------
__global__ void lin_final(const float* __restrict__ X, const float* __restrict__ W,
                          const float* __restrict__ b, float* __restrict__ Y, int N) {
    int idx = blockIdx.x * blockDim.x + threadIdx.x;
    if (idx >= N * OUT_DIM) return;
    int row = idx / OUT_DIM;
    int j = idx - row * OUT_DIM;
    float acc = b[j];
#pragma unroll 8
    for (int k = 0; k < 128; ++k)
        acc = fmaf(X[row * 128 + k], W[k * OUT_DIM + j], acc);
    Y[idx] = acc;
}

extern "C" void kernel_launch(void* const* d_in, const int* in_sizes, int n_in,
                              void* d_out, int out_size, void* d_ws, size_t ws_size,
                              hipStream_t stream) {
    const float* x      = (const float*)d_in[0];
    const int*   eidx   = (const int*)d_in[1];
    const float* enc_w1 = (const float*)d_in[2];
    const float* enc_b1 = (const float*)d_in[3];
    const float* enc_w2 = (const float*)d_in[4];
    const float* enc_b2 = (const float*)d_in[5];
    const float* s1_wl  = (const float*)d_in[6];
    const float* s1_bl  = (const float*)d_in[7];
    const float* s1_wr  = (const float*)d_in[8];
    const float* s2_wl  = (const float*)d_in[9];
    const float* s2_bl  = (const float*)d_in[10];
    const float* s2_wr  = (const float*)d_in[11];
    const float* ro_w1  = (const float*)d_in[12];
    const float* ro_b1  = (const float*)d_in[13];
    const float* ro_w2  = (const float*)d_in[14];
    const float* ro_b2  = (const float*)d_in[15];
    float* out = (float*)d_out;

    const int N = N_NODES;
    const int E = N_EDGES;
    const int* src = eidx;
    const int* dst = eidx + E;

    // Workspace layout (f32)
    char* ws = (char*)d_ws;
    size_t off = 0;
    float* cnt  = (float*)(ws + off); off += ((size_t)N * 4 + 255) & ~255ULL;          // [N]
    float* buf0 = (float*)(ws + off); off += (size_t)N * 128 * 4;                       // [N,128]
    float* bufA = (float*)(ws + off); off += (size_t)N * HID * 4;                       // [N,256]
    float* bufB = (float*)(ws + off); off += (size_t)N * HID * 4;                       // [N,256]
    float* bufC = (float*)(ws + off); off += (size_t)N * HID * 4;                       // [N,256]

    const int nb8   = (N + 7) / 8;
    const int nb128 = (N + 127) / 128;

    // encoder
    lin_tiled<IN_DIM, 128, 8, true><<<nb8, 128, 0, stream>>>(x, enc_w1, enc_b1, buf0, N);
    gemm_rt<128, HID, 0, true><<<dim3(nb128, 2), 256, 0, stream>>>(
        buf0, nullptr, nullptr, enc_w2, nullptr, enc_b2, bufA, N);

    // degree counts (shared across both SAGE layers)
    hipMemsetAsync(cnt, 0, (size_t)N * 4, stream);
    count_kernel<<<(E + 255) / 256, 256, 0, stream>>>(dst, cnt, E);

    // SAGE layer 1: bufA -> bufC
    hipMemsetAsync(bufB, 0, (size_t)N * HID * 4, stream);
    agg_kernel<<<E, HID, 0, stream>>>(bufA, src, dst, bufB, E);
    gemm_rt<512, HID, 1, true><<<dim3(nb128, 2), 256, 0, stream>>>(
        bufB, bufA, cnt, s1_wl, s1_wr, s1_bl, bufC, N);

    // SAGE layer 2: bufC -> bufA
    hipMemsetAsync(bufB, 0, (size_t)N * HID * 4, stream);
    agg_kernel<<<E, HID, 0, stream>>>(bufC, src, dst, bufB, E);
    gemm_rt<512, HID, 1, true><<<dim3(nb128, 2), 256, 0, stream>>>(
        bufB, bufC, cnt, s2_wl, s2_wr, s2_bl, bufA, N);

    // readout
    gemm_rt<HID, 128, 0, true><<<dim3(nb128, 1), 256, 0, stream>>>(
        bufA, nullptr, nullptr, ro_w1, nullptr, ro_b1, buf0, N);
    lin_final<<<(N * OUT_DIM + 255) / 256, 256, 0, stream>>>(buf0, ro_w2, ro_b2, out, N);
}

// Round 3
// 859.885 us; speedup vs baseline: 1.8639x; 1.4871x over previous
//
#include <hip/hip_runtime.h>
#include <hip/hip_bf16.h>

#define N_NODES 50000
#define N_EDGES 400000
#define IN_DIM 24
#define HID 256
#define OUT_DIM 12

// ---------------- Small tiled linear for encoder layer 1 (K=24) ----------------
template<int K, int M, int ROWS, bool RELU>
__global__ __launch_bounds__(M) void lin_tiled(const float* __restrict__ X,
                                               const float* __restrict__ W,
                                               const float* __restrict__ b,
                                               float* __restrict__ Y, int N) {
    __shared__ float xs[ROWS][K];
    const int row0 = blockIdx.x * ROWS;
    const int tid = threadIdx.x;
    for (int i = tid; i < ROWS * K; i += M) {
        int r = i / K, k = i - r * K;
        int gr = row0 + r;
        xs[r][k] = (gr < N) ? X[(long long)gr * K + k] : 0.f;
    }
    __syncthreads();
    const int j = tid;
    float acc[ROWS];
    float bj = b[j];
#pragma unroll
    for (int r = 0; r < ROWS; ++r) acc[r] = bj;
    for (int k = 0; k < K; ++k) {
        float w = W[k * M + j];
#pragma unroll
        for (int r = 0; r < ROWS; ++r) acc[r] = fmaf(xs[r][k], w, acc[r]);
    }
#pragma unroll
    for (int r = 0; r < ROWS; ++r) {
        int gr = row0 + r;
        if (gr < N) {
            float v = RELU ? fmaxf(acc[r], 0.f) : acc[r];
            Y[(long long)gr * M + j] = v;
        }
    }
}

// ---------------- Register-tiled GEMM: Y[N,M] = relu?(X' @ W' + b) ----------------
// MODE 0: X' = X[N,K], W' = W[K,M]
// MODE 1 (SAGE, K=512): X' = concat(mean, h) [N,512], W' = [wl; wr]
// Block: 256 threads as 16x16; BM=128 rows, BN=128 cols, BK=32; 8x8 per thread.
template<int K, int M, int MODE, bool RELU>
__global__ __launch_bounds__(256) void gemm_rt(const float* __restrict__ A,
                                               const float* __restrict__ A2,
                                               const float* __restrict__ W,
                                               const float* __restrict__ W2,
                                               const float* __restrict__ bias,
                                               float* __restrict__ Y, int N) {
    constexpr int BM = 128, BN = 128, BK = 32;
    __shared__ float xs[BM][BK + 4];
    __shared__ float ws[BK][BN + 4];
    const int tid = threadIdx.x;
    const int tx = tid & 15, ty = tid >> 4;
    const int r0 = blockIdx.x * BM;
    const int j0 = blockIdx.y * BN;

    float acc[8][8];
#pragma unroll
    for (int u = 0; u < 8; ++u) {
        float b = bias[j0 + tx + 16 * u];
#pragma unroll
        for (int v = 0; v < 8; ++v) acc[v][u] = b;
    }

    const int srow = tid >> 1;            // 0..127
    const int scol = (tid & 1) * 16;      // 0 or 16
    const int wrow = tid >> 3;            // 0..31
    const int wcol = (tid & 7) * 16;      // 0..112

    for (int kc = 0; kc < K; kc += BK) {
        // ---- stage X tile (BM x BK) ----
        {
            int gr = r0 + srow;
            float4 v0, v1, v2, v3;
            if (gr < N) {
                const float* p;
                int kg = kc + scol;
                if (MODE == 1) {
                    p = (kg < HID) ? (A + (long long)gr * HID + kg)
                                   : (A2 + (long long)gr * HID + (kg - HID));
                } else {
                    p = A + (long long)gr * K + kg;
                }
                v0 = ((const float4*)p)[0];
                v1 = ((const float4*)p)[1];
                v2 = ((const float4*)p)[2];
                v3 = ((const float4*)p)[3];
            } else {
                v0 = v1 = v2 = v3 = make_float4(0.f, 0.f, 0.f, 0.f);
            }
            float* q = &xs[srow][scol];
            ((float4*)q)[0] = v0; ((float4*)q)[1] = v1;
            ((float4*)q)[2] = v2; ((float4*)q)[3] = v3;
        }
        // ---- stage W tile (BK x BN) ----
        {
            int kg = kc + wrow;
            const float* wp;
            if (MODE == 1) {
                wp = (kg < HID) ? (W + (long long)kg * M + j0 + wcol)
                                : (W2 + (long long)(kg - HID) * M + j0 + wcol);
            } else {
                wp = W + (long long)kg * M + j0 + wcol;
            }
            float4 w0 = ((const float4*)wp)[0];
            float4 w1 = ((const float4*)wp)[1];
            float4 w2 = ((const float4*)wp)[2];
            float4 w3 = ((const float4*)wp)[3];
            float* q = &ws[wrow][wcol];
            ((float4*)q)[0] = w0; ((float4*)q)[1] = w1;
            ((float4*)q)[2] = w2; ((float4*)q)[3] = w3;
        }
        __syncthreads();
#pragma unroll 8
        for (int kk = 0; kk < BK; ++kk) {
            float xv[8], wv[8];
#pragma unroll
            for (int v = 0; v < 8; ++v) xv[v] = xs[ty + 16 * v][kk];
#pragma unroll
            for (int u = 0; u < 8; ++u) wv[u] = ws[kk][tx + 16 * u];
#pragma unroll
            for (int v = 0; v < 8; ++v)
#pragma unroll
                for (int u = 0; u < 8; ++u)
                    acc[v][u] = fmaf(xv[v], wv[u], acc[v][u]);
        }
        __syncthreads();
    }

    // ---- epilogue ----
#pragma unroll
    for (int v = 0; v < 8; ++v) {
        int gr = r0 + ty + 16 * v;
        if (gr < N) {
#pragma unroll
            for (int u = 0; u < 8; ++u) {
                float val = acc[v][u];
                if (RELU) val = fmaxf(val, 0.f);
                Y[(long long)gr * M + j0 + tx + 16 * u] = val;
            }
        }
    }
}

// ---------------- CSR build ----------------
__global__ void deg_kernel(const int* __restrict__ dst, int* __restrict__ deg, int E) {
    int e = blockIdx.x * blockDim.x + threadIdx.x;
    if (e < E) atomicAdd(&deg[dst[e]], 1);
}

__global__ __launch_bounds__(1024) void scan_kernel(const int* __restrict__ deg,
                                                    int* __restrict__ rowptr,
                                                    int* __restrict__ cursor, int N) {
    __shared__ int sums[1024];
    const int t = threadIdx.x;
    const int chunk = (N + 1023) / 1024;
    const int lo = t * chunk;
    const int hi = min(lo + chunk, N);
    int s = 0;
    for (int i = lo; i < hi; ++i) s += deg[i];
    sums[t] = s;
    __syncthreads();
    for (int off = 1; off < 1024; off <<= 1) {
        int v = (t >= off) ? sums[t - off] : 0;
        __syncthreads();
        sums[t] += v;
        __syncthreads();
    }
    int excl = (t == 0) ? 0 : sums[t - 1];
    for (int i = lo; i < hi; ++i) {
        rowptr[i] = excl;
        cursor[i] = excl;
        excl += deg[i];
    }
    if (t == 1023) rowptr[N] = sums[1023];
}

__global__ void scatter_kernel(const int* __restrict__ src, const int* __restrict__ dst,
                               int* __restrict__ cursor, int* __restrict__ esrc, int E) {
    int e = blockIdx.x * blockDim.x + threadIdx.x;
    if (e < E) {
        int pos = atomicAdd(&cursor[dst[e]], 1);
        esrc[pos] = src[e];
    }
}

// ---------------- CSR mean-aggregation: mean[n] = (1/max(deg,1)) * sum h[src] ----------------
__global__ __launch_bounds__(256) void agg_csr(const float* __restrict__ h,
                                               const int* __restrict__ rowptr,
                                               const int* __restrict__ esrc,
                                               float* __restrict__ mean, int N) {
    __shared__ int sl[256];
    const int n = blockIdx.x;
    const int c = threadIdx.x;
    const int r0 = rowptr[n];
    const int r1 = rowptr[n + 1];
    float acc = 0.f;
    for (int base = r0; base < r1; base += 256) {
        int m = min(256, r1 - base);
        if (c < m) sl[c] = esrc[base + c];
        __syncthreads();
        int i = 0;
        for (; i + 4 <= m; i += 4) {
            float a0 = h[(long long)sl[i + 0] * HID + c];
            float a1 = h[(long long)sl[i + 1] * HID + c];
            float a2 = h[(long long)sl[i + 2] * HID + c];
            float a3 = h[(long long)sl[i + 3] * HID + c];
            acc += (a0 + a1) + (a2 + a3);
        }
        for (; i < m; ++i) acc += h[(long long)sl[i] * HID + c];
        __syncthreads();
    }
    float inv = 1.0f / fmaxf((float)(r1 - r0), 1.0f);
    mean[(long long)n * HID + c] = acc * inv;
}

// ---------------- Final linear: out[N,12] = h[N,128] @ W[128,12] + b ----------------
__global__ void lin_final(const float* __restrict__ X, const float* __restrict__ W,
                          const float* __restrict__ b, float* __restrict__ Y, int N) {
    int idx = blockIdx.x * blockDim.x + threadIdx.x;
    if (idx >= N * OUT_DIM) return;
    int row = idx / OUT_DIM;
    int j = idx - row * OUT_DIM;
    float acc = b[j];
#pragma unroll 8
    for (int k = 0; k < 128; ++k)
        acc = fmaf(X[row * 128 + k], W[k * OUT_DIM + j], acc);
    Y[idx] = acc;
}

extern "C" void kernel_launch(void* const* d_in, const int* in_sizes, int n_in,
                              void* d_out, int out_size, void* d_ws, size_t ws_size,
                              hipStream_t stream) {
    const float* x      = (const float*)d_in[0];
    const int*   eidx   = (const int*)d_in[1];
    const float* enc_w1 = (const float*)d_in[2];
    const float* enc_b1 = (const float*)d_in[3];
    const float* enc_w2 = (const float*)d_in[4];
    const float* enc_b2 = (const float*)d_in[5];
    const float* s1_wl  = (const float*)d_in[6];
    const float* s1_bl  = (const float*)d_in[7];
    const float* s1_wr  = (const float*)d_in[8];
    const float* s2_wl  = (const float*)d_in[9];
    const float* s2_bl  = (const float*)d_in[10];
    const float* s2_wr  = (const float*)d_in[11];
    const float* ro_w1  = (const float*)d_in[12];
    const float* ro_b1  = (const float*)d_in[13];
    const float* ro_w2  = (const float*)d_in[14];
    const float* ro_b2  = (const float*)d_in[15];
    float* out = (float*)d_out;

    const int N = N_NODES;
    const int E = N_EDGES;
    const int* src = eidx;
    const int* dst = eidx + E;

    // Workspace layout
    char* ws = (char*)d_ws;
    size_t off = 0;
    int* deg     = (int*)(ws + off); off += ((size_t)N * 4 + 255) & ~255ULL;
    int* rowptr  = (int*)(ws + off); off += ((size_t)(N + 1) * 4 + 255) & ~255ULL;
    int* cursor  = (int*)(ws + off); off += ((size_t)N * 4 + 255) & ~255ULL;
    int* esrc    = (int*)(ws + off); off += ((size_t)E * 4 + 255) & ~255ULL;
    float* buf0 = (float*)(ws + off); off += (size_t)N * 128 * 4;  // [N,128]
    float* bufA = (float*)(ws + off); off += (size_t)N * HID * 4;  // [N,256]
    float* bufB = (float*)(ws + off); off += (size_t)N * HID * 4;  // [N,256] mean
    float* bufC = (float*)(ws + off); off += (size_t)N * HID * 4;  // [N,256]

    const int nb8   = (N + 7) / 8;
    const int nb128 = (N + 127) / 128;

    // ---- CSR build (once; shared by both SAGE layers) ----
    hipMemsetAsync(deg, 0, (size_t)N * 4, stream);
    deg_kernel<<<(E + 255) / 256, 256, 0, stream>>>(dst, deg, E);
    scan_kernel<<<1, 1024, 0, stream>>>(deg, rowptr, cursor, N);
    scatter_kernel<<<(E + 255) / 256, 256, 0, stream>>>(src, dst, cursor, esrc, E);

    // ---- encoder ----
    lin_tiled<IN_DIM, 128, 8, true><<<nb8, 128, 0, stream>>>(x, enc_w1, enc_b1, buf0, N);
    gemm_rt<128, HID, 0, true><<<dim3(nb128, 2), 256, 0, stream>>>(
        buf0, nullptr, enc_w2, nullptr, enc_b2, bufA, N);

    // ---- SAGE layer 1: bufA -> bufC ----
    agg_csr<<<N, 256, 0, stream>>>(bufA, rowptr, esrc, bufB, N);
    gemm_rt<512, HID, 1, true><<<dim3(nb128, 2), 256, 0, stream>>>(
        bufB, bufA, s1_wl, s1_wr, s1_bl, bufC, N);

    // ---- SAGE layer 2: bufC -> bufA ----
    agg_csr<<<N, 256, 0, stream>>>(bufC, rowptr, esrc, bufB, N);
    gemm_rt<512, HID, 1, true><<<dim3(nb128, 2), 256, 0, stream>>>(
        bufB, bufC, s2_wl, s2_wr, s2_bl, bufA, N);

    // ---- readout ----
    gemm_rt<HID, 128, 0, true><<<dim3(nb128, 1), 256, 0, stream>>>(
        bufA, nullptr, ro_w1, nullptr, ro_b1, buf0, N);
    lin_final<<<(N * OUT_DIM + 255) / 256, 256, 0, stream>>>(buf0, ro_w2, ro_b2, out, N);
}

// Round 4
// 557.948 us; speedup vs baseline: 2.8726x; 1.5412x over previous
//
#include <hip/hip_runtime.h>
#include <hip/hip_bf16.h>

#define N_NODES 50000
#define N_EDGES 400000
#define IN_DIM 24
#define HID 256
#define OUT_DIM 12

typedef __attribute__((ext_vector_type(8))) short short8;
typedef __attribute__((ext_vector_type(4))) float f32x4;

// async global->LDS, 16 bytes per lane (dest must be linear: base + lane*16 per wave)
__device__ __forceinline__ void gload_lds16(const void* g, void* l) {
    typedef __attribute__((address_space(3))) unsigned int u32_lds;
    typedef const __attribute__((address_space(1))) unsigned int u32_glb;
    __builtin_amdgcn_global_load_lds((u32_glb*)(unsigned long long)g,
                                     (u32_lds*)(unsigned int)(unsigned long long)l,
                                     16, 0, 0);
}

__device__ __forceinline__ void split_store(float v, __hip_bfloat16* hi, __hip_bfloat16* lo, size_t o) {
    __hip_bfloat16 h = __float2bfloat16(v);
    hi[o] = h;
    lo[o] = __float2bfloat16(v - __bfloat162float(h));
}

// ---------------- encoder layer 1 (K=24, f32 compute, bf16 hi/lo out) ----------------
template<int K, int M, int ROWS>
__global__ __launch_bounds__(M) void lin_enc1(const float* __restrict__ X,
                                              const float* __restrict__ W,
                                              const float* __restrict__ b,
                                              __hip_bfloat16* __restrict__ Yhi,
                                              __hip_bfloat16* __restrict__ Ylo, int N) {
    __shared__ float xs[ROWS][K];
    const int row0 = blockIdx.x * ROWS;
    const int tid = threadIdx.x;
    for (int i = tid; i < ROWS * K; i += M) {
        int r = i / K, k = i - r * K;
        int gr = row0 + r;
        xs[r][k] = (gr < N) ? X[(long long)gr * K + k] : 0.f;
    }
    __syncthreads();
    const int j = tid;
    float acc[ROWS];
    float bj = b[j];
#pragma unroll
    for (int r = 0; r < ROWS; ++r) acc[r] = bj;
    for (int k = 0; k < K; ++k) {
        float w = W[k * M + j];
#pragma unroll
        for (int r = 0; r < ROWS; ++r) acc[r] = fmaf(xs[r][k], w, acc[r]);
    }
#pragma unroll
    for (int r = 0; r < ROWS; ++r) {
        int gr = row0 + r;
        if (gr < N) {
            float v = fmaxf(acc[r], 0.f);
            split_store(v, Yhi, Ylo, (size_t)gr * M + j);
        }
    }
}

// ---------------- weight transpose + hi/lo split: Wt[j][k] = W[k][j] ----------------
__global__ void wtrans(const float* __restrict__ W1, const float* __restrict__ W2,
                       int K1, int K, int M,
                       __hip_bfloat16* __restrict__ Whi, __hip_bfloat16* __restrict__ Wlo) {
    int idx = blockIdx.x * blockDim.x + threadIdx.x;
    if (idx >= M * K) return;
    int j = idx / K, k = idx - j * K;
    float v = (k < K1) ? W1[(size_t)k * M + j] : W2[(size_t)(k - K1) * M + j];
    split_store(v, Whi, Wlo, idx);
}

// ---------------- MFMA split-bf16 GEMM ----------------
// C[r][j] = relu?( sum_k X[r][k] * Wt[j][k] + bias[j] ), X ~ hi+lo, Wt ~ hi+lo
// MODE 0: X rows from (Ahi,Alo) [N][K]
// MODE 1: k<HID from (Ahi,Alo) [N][HID] (mean), else (A2hi,A2lo) [N][HID] (h)
// Block 256 thr = 4 waves (2x2), tile 128x128, wave tile 64x64 (4x4 frags 16x16), BK=32.
template<int K, int MODE, bool WF32, bool WBF16, bool RELU>
__global__ __launch_bounds__(256, 2) void gemm_mfma(
    const __hip_bfloat16* __restrict__ Ahi, const __hip_bfloat16* __restrict__ Alo,
    const __hip_bfloat16* __restrict__ A2hi, const __hip_bfloat16* __restrict__ A2lo,
    const __hip_bfloat16* __restrict__ Whi, const __hip_bfloat16* __restrict__ Wlo,
    const float* __restrict__ bias,
    float* __restrict__ Yf, __hip_bfloat16* __restrict__ Yhi, __hip_bfloat16* __restrict__ Ylo,
    int N, int M) {
    __shared__ __align__(16) short lds[4][128 * 32];  // 0=Ahi 1=Alo 2=Bhi 3=Blo, [row][k]
    const int tid = threadIdx.x;
    const int r0 = blockIdx.x * 128;
    const int j0 = blockIdx.y * 128;
    const int w = tid >> 6, lane = tid & 63;
    const int wr = w >> 1, wc = w & 1;
    const int lrow = lane & 15, lg = lane >> 4;

    f32x4 acc[4][4] = {};

    const int crow = tid >> 2;   // staging row 0..63 (+64 second pass)
    const int cg = tid & 3;      // 16B chunk within 64B row

    for (int kc = 0; kc < K; kc += 32) {
        __syncthreads();
        // ---- stage A tiles ----
        const __hip_bfloat16 *pah, *pal;
        int ka, KA;
        if (MODE == 1) {
            KA = HID;
            if (kc >= HID) { pah = A2hi; pal = A2lo; ka = kc - HID; }
            else           { pah = Ahi;  pal = Alo;  ka = kc; }
        } else {
            KA = K; pah = Ahi; pal = Alo; ka = kc;
        }
#pragma unroll
        for (int it = 0; it < 2; ++it) {
            int row = crow + it * 64;
            int gr = r0 + row; if (gr > N - 1) gr = N - 1;
            size_t go = (size_t)gr * KA + ka + cg * 8;
            int lo_off = (row * 4 + cg) * 8;
            gload_lds16(pah + go, &lds[0][lo_off]);
            gload_lds16(pal + go, &lds[1][lo_off]);
        }
        // ---- stage B tiles (Wt rows = output cols) ----
#pragma unroll
        for (int it = 0; it < 2; ++it) {
            int row = crow + it * 64;
            size_t go = (size_t)(j0 + row) * K + kc + cg * 8;
            int lo_off = (row * 4 + cg) * 8;
            gload_lds16(Whi + go, &lds[2][lo_off]);
            gload_lds16(Wlo + go, &lds[3][lo_off]);
        }
        __syncthreads();

        short8 ah[4], al[4], bh[4], bl[4];
#pragma unroll
        for (int f = 0; f < 4; ++f) {
            int ar = wr * 64 + f * 16 + lrow;
            ah[f] = *(const short8*)&lds[0][ar * 32 + lg * 8];
            al[f] = *(const short8*)&lds[1][ar * 32 + lg * 8];
            int br = wc * 64 + f * 16 + lrow;
            bh[f] = *(const short8*)&lds[2][br * 32 + lg * 8];
            bl[f] = *(const short8*)&lds[3][br * 32 + lg * 8];
        }
#pragma unroll
        for (int fi = 0; fi < 4; ++fi)
#pragma unroll
            for (int fj = 0; fj < 4; ++fj) {
                acc[fi][fj] = __builtin_amdgcn_mfma_f32_16x16x32_bf16(ah[fi], bh[fj], acc[fi][fj], 0, 0, 0);
                acc[fi][fj] = __builtin_amdgcn_mfma_f32_16x16x32_bf16(al[fi], bh[fj], acc[fi][fj], 0, 0, 0);
                acc[fi][fj] = __builtin_amdgcn_mfma_f32_16x16x32_bf16(ah[fi], bl[fj], acc[fi][fj], 0, 0, 0);
            }
    }

    // ---- epilogue: C/D layout col=lane&15, row=(lane>>4)*4+reg ----
#pragma unroll
    for (int fj = 0; fj < 4; ++fj) {
        int ocol = j0 + wc * 64 + fj * 16 + lrow;
        float bv = bias[ocol];
#pragma unroll
        for (int fi = 0; fi < 4; ++fi) {
#pragma unroll
            for (int r = 0; r < 4; ++r) {
                int orow = r0 + wr * 64 + fi * 16 + lg * 4 + r;
                if (orow < N) {
                    float v = acc[fi][fj][r] + bv;
                    if (RELU) v = fmaxf(v, 0.f);
                    size_t o = (size_t)orow * M + ocol;
                    if (WF32) Yf[o] = v;
                    if (WBF16) split_store(v, Yhi, Ylo, o);
                }
            }
        }
    }
}

// ---------------- CSR build ----------------
__global__ void deg_kernel(const int* __restrict__ dst, int* __restrict__ deg, int E) {
    int e = blockIdx.x * blockDim.x + threadIdx.x;
    if (e < E) atomicAdd(&deg[dst[e]], 1);
}

__global__ __launch_bounds__(1024) void scan_kernel(const int* __restrict__ deg,
                                                    int* __restrict__ rowptr,
                                                    int* __restrict__ cursor, int N) {
    __shared__ int sums[1024];
    const int t = threadIdx.x;
    const int chunk = (N + 1023) / 1024;
    const int lo = t * chunk;
    const int hi = min(lo + chunk, N);
    int s = 0;
    for (int i = lo; i < hi; ++i) s += deg[i];
    sums[t] = s;
    __syncthreads();
    for (int off = 1; off < 1024; off <<= 1) {
        int v = (t >= off) ? sums[t - off] : 0;
        __syncthreads();
        sums[t] += v;
        __syncthreads();
    }
    int excl = (t == 0) ? 0 : sums[t - 1];
    for (int i = lo; i < hi; ++i) {
        rowptr[i] = excl;
        cursor[i] = excl;
        excl += deg[i];
    }
    if (t == 1023) rowptr[N] = sums[1023];
}

__global__ void scatter_kernel(const int* __restrict__ src, const int* __restrict__ dst,
                               int* __restrict__ cursor, int* __restrict__ esrc, int E) {
    int e = blockIdx.x * blockDim.x + threadIdx.x;
    if (e < E) {
        int pos = atomicAdd(&cursor[dst[e]], 1);
        esrc[pos] = src[e];
    }
}

// ---------------- CSR mean-aggregation, bf16 hi/lo output ----------------
__global__ __launch_bounds__(256) void agg_csr(const float* __restrict__ h,
                                               const int* __restrict__ rowptr,
                                               const int* __restrict__ esrc,
                                               __hip_bfloat16* __restrict__ mhi,
                                               __hip_bfloat16* __restrict__ mlo, int N) {
    __shared__ int sl[256];
    const int n = blockIdx.x;
    const int c = threadIdx.x;
    const int r0 = rowptr[n];
    const int r1 = rowptr[n + 1];
    float acc = 0.f;
    for (int base = r0; base < r1; base += 256) {
        int m = min(256, r1 - base);
        if (c < m) sl[c] = esrc[base + c];
        __syncthreads();
        int i = 0;
        for (; i + 4 <= m; i += 4) {
            float a0 = h[(long long)sl[i + 0] * HID + c];
            float a1 = h[(long long)sl[i + 1] * HID + c];
            float a2 = h[(long long)sl[i + 2] * HID + c];
            float a3 = h[(long long)sl[i + 3] * HID + c];
            acc += (a0 + a1) + (a2 + a3);
        }
        for (; i < m; ++i) acc += h[(long long)sl[i] * HID + c];
        __syncthreads();
    }
    float inv = 1.0f / fmaxf((float)(r1 - r0), 1.0f);
    split_store(acc * inv, mhi, mlo, (size_t)n * HID + c);
}

// ---------------- Final linear: out[N,12] = h[N,128] @ W[128,12] + b ----------------
__global__ void lin_final(const float* __restrict__ X, const float* __restrict__ W,
                          const float* __restrict__ b, float* __restrict__ Y, int N) {
    int idx = blockIdx.x * blockDim.x + threadIdx.x;
    if (idx >= N * OUT_DIM) return;
    int row = idx / OUT_DIM;
    int j = idx - row * OUT_DIM;
    float acc = b[j];
#pragma unroll 8
    for (int k = 0; k < 128; ++k)
        acc = fmaf(X[row * 128 + k], W[k * OUT_DIM + j], acc);
    Y[idx] = acc;
}

extern "C" void kernel_launch(void* const* d_in, const int* in_sizes, int n_in,
                              void* d_out, int out_size, void* d_ws, size_t ws_size,
                              hipStream_t stream) {
    const float* x      = (const float*)d_in[0];
    const int*   eidx   = (const int*)d_in[1];
    const float* enc_w1 = (const float*)d_in[2];
    const float* enc_b1 = (const float*)d_in[3];
    const float* enc_w2 = (const float*)d_in[4];
    const float* enc_b2 = (const float*)d_in[5];
    const float* s1_wl  = (const float*)d_in[6];
    const float* s1_bl  = (const float*)d_in[7];
    const float* s1_wr  = (const float*)d_in[8];
    const float* s2_wl  = (const float*)d_in[9];
    const float* s2_bl  = (const float*)d_in[10];
    const float* s2_wr  = (const float*)d_in[11];
    const float* ro_w1  = (const float*)d_in[12];
    const float* ro_b1  = (const float*)d_in[13];
    const float* ro_w2  = (const float*)d_in[14];
    const float* ro_b2  = (const float*)d_in[15];
    float* out = (float*)d_out;

    const int N = N_NODES;
    const int E = N_EDGES;
    const int* src = eidx;
    const int* dst = eidx + E;

    typedef __hip_bfloat16 bf16;
    char* ws = (char*)d_ws;
    size_t off = 0;
    auto alloc = [&](size_t bytes) { void* p = ws + off; off += (bytes + 255) & ~255ULL; return p; };
    int* deg    = (int*)alloc((size_t)N * 4);
    int* rowptr = (int*)alloc((size_t)(N + 1) * 4);
    int* cursor = (int*)alloc((size_t)N * 4);
    int* esrc   = (int*)alloc((size_t)E * 4);
    bf16* wtE_hi = (bf16*)alloc((size_t)256 * 128 * 2);
    bf16* wtE_lo = (bf16*)alloc((size_t)256 * 128 * 2);
    bf16* wtS1_hi = (bf16*)alloc((size_t)256 * 512 * 2);
    bf16* wtS1_lo = (bf16*)alloc((size_t)256 * 512 * 2);
    bf16* wtS2_hi = (bf16*)alloc((size_t)256 * 512 * 2);
    bf16* wtS2_lo = (bf16*)alloc((size_t)256 * 512 * 2);
    bf16* wtR_hi = (bf16*)alloc((size_t)128 * 256 * 2);
    bf16* wtR_lo = (bf16*)alloc((size_t)128 * 256 * 2);
    bf16* h0_hi = (bf16*)alloc((size_t)N * 128 * 2);
    bf16* h0_lo = (bf16*)alloc((size_t)N * 128 * 2);
    float* f32buf = (float*)alloc((size_t)N * HID * 4);      // h1, then h2, then h4
    bf16* hA_hi = (bf16*)alloc((size_t)N * HID * 2);         // h1, then h3
    bf16* hA_lo = (bf16*)alloc((size_t)N * HID * 2);
    bf16* hB_hi = (bf16*)alloc((size_t)N * HID * 2);         // h2
    bf16* hB_lo = (bf16*)alloc((size_t)N * HID * 2);
    bf16* m_hi = (bf16*)alloc((size_t)N * HID * 2);          // mean (both layers)
    bf16* m_lo = (bf16*)alloc((size_t)N * HID * 2);

    const int nb8 = (N + 7) / 8;
    const int gx = (N + 127) / 128;

    // ---- CSR build ----
    hipMemsetAsync(deg, 0, (size_t)N * 4, stream);
    deg_kernel<<<(E + 255) / 256, 256, 0, stream>>>(dst, deg, E);
    scan_kernel<<<1, 1024, 0, stream>>>(deg, rowptr, cursor, N);
    scatter_kernel<<<(E + 255) / 256, 256, 0, stream>>>(src, dst, cursor, esrc, E);

    // ---- weight transpose + split ----
    wtrans<<<(256 * 128 + 255) / 256, 256, 0, stream>>>(enc_w2, nullptr, 128, 128, 256, wtE_hi, wtE_lo);
    wtrans<<<(256 * 512 + 255) / 256, 256, 0, stream>>>(s1_wl, s1_wr, 256, 512, 256, wtS1_hi, wtS1_lo);
    wtrans<<<(256 * 512 + 255) / 256, 256, 0, stream>>>(s2_wl, s2_wr, 256, 512, 256, wtS2_hi, wtS2_lo);
    wtrans<<<(128 * 256 + 255) / 256, 256, 0, stream>>>(ro_w1, nullptr, 256, 256, 128, wtR_hi, wtR_lo);

    // ---- encoder ----
    lin_enc1<IN_DIM, 128, 8><<<nb8, 128, 0, stream>>>(x, enc_w1, enc_b1, h0_hi, h0_lo, N);
    gemm_mfma<128, 0, true, true, true><<<dim3(gx, 2), 256, 0, stream>>>(
        h0_hi, h0_lo, nullptr, nullptr, wtE_hi, wtE_lo, enc_b2, f32buf, hA_hi, hA_lo, N, 256);

    // ---- SAGE 1 ----
    agg_csr<<<N, 256, 0, stream>>>(f32buf, rowptr, esrc, m_hi, m_lo, N);
    gemm_mfma<512, 1, true, true, true><<<dim3(gx, 2), 256, 0, stream>>>(
        m_hi, m_lo, hA_hi, hA_lo, wtS1_hi, wtS1_lo, s1_bl, f32buf, hB_hi, hB_lo, N, 256);

    // ---- SAGE 2 ----
    agg_csr<<<N, 256, 0, stream>>>(f32buf, rowptr, esrc, m_hi, m_lo, N);
    gemm_mfma<512, 1, false, true, true><<<dim3(gx, 2), 256, 0, stream>>>(
        m_hi, m_lo, hB_hi, hB_lo, wtS2_hi, wtS2_lo, s2_bl, nullptr, hA_hi, hA_lo, N, 256);

    // ---- readout ----
    gemm_mfma<256, 0, true, false, true><<<dim3(gx, 1), 256, 0, stream>>>(
        hA_hi, hA_lo, nullptr, nullptr, wtR_hi, wtR_lo, ro_b1, f32buf, nullptr, nullptr, N, 128);
    lin_final<<<(N * OUT_DIM + 255) / 256, 256, 0, stream>>>(f32buf, ro_w2, ro_b2, out, N);
}

// Round 5
// 460.138 us; speedup vs baseline: 3.4832x; 1.2126x over previous
//
#include <hip/hip_runtime.h>
#include <hip/hip_bf16.h>

#define N_NODES 50000
#define N_EDGES 400000
#define IN_DIM 24
#define HID 256
#define OUT_DIM 12

typedef __attribute__((ext_vector_type(8))) short short8;
typedef __attribute__((ext_vector_type(4))) float f32x4;

// async global->LDS, 16 bytes per lane (dest must be linear: base + lane*16 per wave)
__device__ __forceinline__ void gload_lds16(const void* g, void* l) {
    typedef __attribute__((address_space(3))) unsigned int u32_lds;
    typedef const __attribute__((address_space(1))) unsigned int u32_glb;
    __builtin_amdgcn_global_load_lds((u32_glb*)(unsigned long long)g,
                                     (u32_lds*)(unsigned int)(unsigned long long)l,
                                     16, 0, 0);
}

__device__ __forceinline__ void split_store(float v, __hip_bfloat16* hi, __hip_bfloat16* lo, size_t o) {
    __hip_bfloat16 h = __float2bfloat16(v);
    hi[o] = h;
    lo[o] = __float2bfloat16(v - __bfloat162float(h));
}

// ---------------- encoder layer 1 (K=24, f32 compute, bf16 hi/lo out) ----------------
template<int K, int M, int ROWS>
__global__ __launch_bounds__(M) void lin_enc1(const float* __restrict__ X,
                                              const float* __restrict__ W,
                                              const float* __restrict__ b,
                                              __hip_bfloat16* __restrict__ Yhi,
                                              __hip_bfloat16* __restrict__ Ylo, int N) {
    __shared__ float xs[ROWS][K];
    const int row0 = blockIdx.x * ROWS;
    const int tid = threadIdx.x;
    for (int i = tid; i < ROWS * K; i += M) {
        int r = i / K, k = i - r * K;
        int gr = row0 + r;
        xs[r][k] = (gr < N) ? X[(long long)gr * K + k] : 0.f;
    }
    __syncthreads();
    const int j = tid;
    float acc[ROWS];
    float bj = b[j];
#pragma unroll
    for (int r = 0; r < ROWS; ++r) acc[r] = bj;
    for (int k = 0; k < K; ++k) {
        float w = W[k * M + j];
#pragma unroll
        for (int r = 0; r < ROWS; ++r) acc[r] = fmaf(xs[r][k], w, acc[r]);
    }
#pragma unroll
    for (int r = 0; r < ROWS; ++r) {
        int gr = row0 + r;
        if (gr < N) {
            float v = fmaxf(acc[r], 0.f);
            split_store(v, Yhi, Ylo, (size_t)gr * M + j);
        }
    }
}

// ---------------- weight transpose + hi/lo split: Wt[j][k] = W[k][j] ----------------
__global__ void wtrans(const float* __restrict__ W1, const float* __restrict__ W2,
                       int K1, int K, int M,
                       __hip_bfloat16* __restrict__ Whi, __hip_bfloat16* __restrict__ Wlo) {
    int idx = blockIdx.x * blockDim.x + threadIdx.x;
    if (idx >= M * K) return;
    int j = idx / K, k = idx - j * K;
    float v = (k < K1) ? W1[(size_t)k * M + j] : W2[(size_t)(k - K1) * M + j];
    split_store(v, Whi, Wlo, idx);
}

// ---------------- MFMA split-bf16 GEMM ----------------
template<int K, int MODE, bool WF32, bool WBF16, bool RELU>
__global__ __launch_bounds__(256, 2) void gemm_mfma(
    const __hip_bfloat16* __restrict__ Ahi, const __hip_bfloat16* __restrict__ Alo,
    const __hip_bfloat16* __restrict__ A2hi, const __hip_bfloat16* __restrict__ A2lo,
    const __hip_bfloat16* __restrict__ Whi, const __hip_bfloat16* __restrict__ Wlo,
    const float* __restrict__ bias,
    float* __restrict__ Yf, __hip_bfloat16* __restrict__ Yhi, __hip_bfloat16* __restrict__ Ylo,
    int N, int M) {
    __shared__ __align__(16) short lds[4][128 * 32];  // 0=Ahi 1=Alo 2=Bhi 3=Blo, [row][k]
    const int tid = threadIdx.x;
    const int r0 = blockIdx.x * 128;
    const int j0 = blockIdx.y * 128;
    const int w = tid >> 6, lane = tid & 63;
    const int wr = w >> 1, wc = w & 1;
    const int lrow = lane & 15, lg = lane >> 4;

    f32x4 acc[4][4] = {};

    const int crow = tid >> 2;   // staging row 0..63 (+64 second pass)
    const int cg = tid & 3;      // 16B chunk within 64B row

    for (int kc = 0; kc < K; kc += 32) {
        __syncthreads();
        // ---- stage A tiles ----
        const __hip_bfloat16 *pah, *pal;
        int ka, KA;
        if (MODE == 1) {
            KA = HID;
            if (kc >= HID) { pah = A2hi; pal = A2lo; ka = kc - HID; }
            else           { pah = Ahi;  pal = Alo;  ka = kc; }
        } else {
            KA = K; pah = Ahi; pal = Alo; ka = kc;
        }
#pragma unroll
        for (int it = 0; it < 2; ++it) {
            int row = crow + it * 64;
            int gr = r0 + row; if (gr > N - 1) gr = N - 1;
            size_t go = (size_t)gr * KA + ka + cg * 8;
            int lo_off = (row * 4 + cg) * 8;
            gload_lds16(pah + go, &lds[0][lo_off]);
            gload_lds16(pal + go, &lds[1][lo_off]);
        }
        // ---- stage B tiles (Wt rows = output cols) ----
#pragma unroll
        for (int it = 0; it < 2; ++it) {
            int row = crow + it * 64;
            size_t go = (size_t)(j0 + row) * K + kc + cg * 8;
            int lo_off = (row * 4 + cg) * 8;
            gload_lds16(Whi + go, &lds[2][lo_off]);
            gload_lds16(Wlo + go, &lds[3][lo_off]);
        }
        __syncthreads();

        short8 ah[4], al[4], bh[4], bl[4];
#pragma unroll
        for (int f = 0; f < 4; ++f) {
            int ar = wr * 64 + f * 16 + lrow;
            ah[f] = *(const short8*)&lds[0][ar * 32 + lg * 8];
            al[f] = *(const short8*)&lds[1][ar * 32 + lg * 8];
            int br = wc * 64 + f * 16 + lrow;
            bh[f] = *(const short8*)&lds[2][br * 32 + lg * 8];
            bl[f] = *(const short8*)&lds[3][br * 32 + lg * 8];
        }
#pragma unroll
        for (int fi = 0; fi < 4; ++fi)
#pragma unroll
            for (int fj = 0; fj < 4; ++fj) {
                acc[fi][fj] = __builtin_amdgcn_mfma_f32_16x16x32_bf16(ah[fi], bh[fj], acc[fi][fj], 0, 0, 0);
                acc[fi][fj] = __builtin_amdgcn_mfma_f32_16x16x32_bf16(al[fi], bh[fj], acc[fi][fj], 0, 0, 0);
                acc[fi][fj] = __builtin_amdgcn_mfma_f32_16x16x32_bf16(ah[fi], bl[fj], acc[fi][fj], 0, 0, 0);
            }
    }

    // ---- epilogue: C/D layout col=lane&15, row=(lane>>4)*4+reg ----
#pragma unroll
    for (int fj = 0; fj < 4; ++fj) {
        int ocol = j0 + wc * 64 + fj * 16 + lrow;
        float bv = bias[ocol];
#pragma unroll
        for (int fi = 0; fi < 4; ++fi) {
#pragma unroll
            for (int r = 0; r < 4; ++r) {
                int orow = r0 + wr * 64 + fi * 16 + lg * 4 + r;
                if (orow < N) {
                    float v = acc[fi][fj][r] + bv;
                    if (RELU) v = fmaxf(v, 0.f);
                    size_t o = (size_t)orow * M + ocol;
                    if (WF32) Yf[o] = v;
                    if (WBF16) split_store(v, Yhi, Ylo, o);
                }
            }
        }
    }
}

// ---------------- CSR build ----------------
__global__ void deg_kernel(const int* __restrict__ dst, int* __restrict__ deg, int E) {
    int e = blockIdx.x * blockDim.x + threadIdx.x;
    if (e < E) atomicAdd(&deg[dst[e]], 1);
}

// Stage 1: per-block inclusive scan (256 elems/block) + block total
__global__ __launch_bounds__(256) void scan_local(const int* __restrict__ deg,
                                                  int* __restrict__ locincl,
                                                  int* __restrict__ bsum, int N) {
    const int t = threadIdx.x;
    const int i = blockIdx.x * 256 + t;
    int v = (i < N) ? deg[i] : 0;
    const int lane = t & 63;
    int x = v;
#pragma unroll
    for (int off = 1; off < 64; off <<= 1) {
        int y = __shfl_up(x, off, 64);
        if (lane >= off) x += y;
    }
    __shared__ int wsum[4];
    if (lane == 63) wsum[t >> 6] = x;
    __syncthreads();
    const int wid = t >> 6;
    int add = 0;
    for (int wI = 0; wI < wid; ++wI) add += wsum[wI];
    x += add;
    if (i < N) locincl[i] = x;
    if (t == 255) bsum[blockIdx.x] = x;
}

// Stage 2: exclusive scan of block sums (B <= 256), single block
__global__ __launch_bounds__(256) void scan_bsum(int* __restrict__ bsum, int B) {
    const int t = threadIdx.x;
    int v = (t < B) ? bsum[t] : 0;
    const int lane = t & 63;
    int x = v;
#pragma unroll
    for (int off = 1; off < 64; off <<= 1) {
        int y = __shfl_up(x, off, 64);
        if (lane >= off) x += y;
    }
    __shared__ int wsum[4];
    if (lane == 63) wsum[t >> 6] = x;
    __syncthreads();
    const int wid = t >> 6;
    int add = 0;
    for (int wI = 0; wI < wid; ++wI) add += wsum[wI];
    x += add;
    if (t < B) bsum[t] = x - v;   // exclusive
}

// Stage 3: recombine -> exclusive rowptr + cursor
__global__ __launch_bounds__(256) void scan_final(const int* __restrict__ deg,
                                                  const int* __restrict__ locincl,
                                                  const int* __restrict__ bsum,
                                                  int* __restrict__ rowptr,
                                                  int* __restrict__ cursor, int N, int E) {
    const int i = blockIdx.x * 256 + threadIdx.x;
    if (i < N) {
        int excl = bsum[blockIdx.x] + locincl[i] - deg[i];
        rowptr[i] = excl;
        cursor[i] = excl;
    }
    if (i == 0) rowptr[N] = E;
}

__global__ void scatter_kernel(const int* __restrict__ src, const int* __restrict__ dst,
                               int* __restrict__ cursor, int* __restrict__ esrc, int E) {
    int e = blockIdx.x * blockDim.x + threadIdx.x;
    if (e < E) {
        int pos = atomicAdd(&cursor[dst[e]], 1);
        esrc[pos] = src[e];
    }
}

// ---------------- CSR mean-aggregation, bf16 hi/lo output ----------------
__global__ __launch_bounds__(256) void agg_csr(const float* __restrict__ h,
                                               const int* __restrict__ rowptr,
                                               const int* __restrict__ esrc,
                                               __hip_bfloat16* __restrict__ mhi,
                                               __hip_bfloat16* __restrict__ mlo, int N) {
    __shared__ int sl[256];
    const int n = blockIdx.x;
    const int c = threadIdx.x;
    const int r0 = rowptr[n];
    const int r1 = rowptr[n + 1];
    float acc = 0.f;
    for (int base = r0; base < r1; base += 256) {
        int m = min(256, r1 - base);
        if (c < m) sl[c] = esrc[base + c];
        __syncthreads();
        int i = 0;
        for (; i + 4 <= m; i += 4) {
            float a0 = h[(long long)sl[i + 0] * HID + c];
            float a1 = h[(long long)sl[i + 1] * HID + c];
            float a2 = h[(long long)sl[i + 2] * HID + c];
            float a3 = h[(long long)sl[i + 3] * HID + c];
            acc += (a0 + a1) + (a2 + a3);
        }
        for (; i < m; ++i) acc += h[(long long)sl[i] * HID + c];
        __syncthreads();
    }
    float inv = 1.0f / fmaxf((float)(r1 - r0), 1.0f);
    split_store(acc * inv, mhi, mlo, (size_t)n * HID + c);
}

// ---------------- Final linear: out[N,12] = h[N,128] @ W[128,12] + b ----------------
__global__ void lin_final(const float* __restrict__ X, const float* __restrict__ W,
                          const float* __restrict__ b, float* __restrict__ Y, int N) {
    int idx = blockIdx.x * blockDim.x + threadIdx.x;
    if (idx >= N * OUT_DIM) return;
    int row = idx / OUT_DIM;
    int j = idx - row * OUT_DIM;
    float acc = b[j];
#pragma unroll 8
    for (int k = 0; k < 128; ++k)
        acc = fmaf(X[row * 128 + k], W[k * OUT_DIM + j], acc);
    Y[idx] = acc;
}

extern "C" void kernel_launch(void* const* d_in, const int* in_sizes, int n_in,
                              void* d_out, int out_size, void* d_ws, size_t ws_size,
                              hipStream_t stream) {
    const float* x      = (const float*)d_in[0];
    const int*   eidx   = (const int*)d_in[1];
    const float* enc_w1 = (const float*)d_in[2];
    const float* enc_b1 = (const float*)d_in[3];
    const float* enc_w2 = (const float*)d_in[4];
    const float* enc_b2 = (const float*)d_in[5];
    const float* s1_wl  = (const float*)d_in[6];
    const float* s1_bl  = (const float*)d_in[7];
    const float* s1_wr  = (const float*)d_in[8];
    const float* s2_wl  = (const float*)d_in[9];
    const float* s2_bl  = (const float*)d_in[10];
    const float* s2_wr  = (const float*)d_in[11];
    const float* ro_w1  = (const float*)d_in[12];
    const float* ro_b1  = (const float*)d_in[13];
    const float* ro_w2  = (const float*)d_in[14];
    const float* ro_b2  = (const float*)d_in[15];
    float* out = (float*)d_out;

    const int N = N_NODES;
    const int E = N_EDGES;
    const int* src = eidx;
    const int* dst = eidx + E;

    typedef __hip_bfloat16 bf16;
    char* ws = (char*)d_ws;
    size_t off = 0;
    auto alloc = [&](size_t bytes) { void* p = ws + off; off += (bytes + 255) & ~255ULL; return p; };
    int* deg     = (int*)alloc((size_t)N * 4);
    int* rowptr  = (int*)alloc((size_t)(N + 1) * 4);
    int* cursor  = (int*)alloc((size_t)N * 4);
    int* esrc    = (int*)alloc((size_t)E * 4);
    int* locincl = (int*)alloc((size_t)N * 4);
    int* bsum    = (int*)alloc((size_t)256 * 4);
    bf16* wtE_hi = (bf16*)alloc((size_t)256 * 128 * 2);
    bf16* wtE_lo = (bf16*)alloc((size_t)256 * 128 * 2);
    bf16* wtS1_hi = (bf16*)alloc((size_t)256 * 512 * 2);
    bf16* wtS1_lo = (bf16*)alloc((size_t)256 * 512 * 2);
    bf16* wtS2_hi = (bf16*)alloc((size_t)256 * 512 * 2);
    bf16* wtS2_lo = (bf16*)alloc((size_t)256 * 512 * 2);
    bf16* wtR_hi = (bf16*)alloc((size_t)128 * 256 * 2);
    bf16* wtR_lo = (bf16*)alloc((size_t)128 * 256 * 2);
    bf16* h0_hi = (bf16*)alloc((size_t)N * 128 * 2);
    bf16* h0_lo = (bf16*)alloc((size_t)N * 128 * 2);
    float* f32buf = (float*)alloc((size_t)N * HID * 4);
    bf16* hA_hi = (bf16*)alloc((size_t)N * HID * 2);
    bf16* hA_lo = (bf16*)alloc((size_t)N * HID * 2);
    bf16* hB_hi = (bf16*)alloc((size_t)N * HID * 2);
    bf16* hB_lo = (bf16*)alloc((size_t)N * HID * 2);
    bf16* m_hi = (bf16*)alloc((size_t)N * HID * 2);
    bf16* m_lo = (bf16*)alloc((size_t)N * HID * 2);

    const int nb8 = (N + 7) / 8;
    const int gx = (N + 127) / 128;
    const int nbScan = (N + 255) / 256;

    // ---- CSR build ----
    hipMemsetAsync(deg, 0, (size_t)N * 4, stream);
    deg_kernel<<<(E + 255) / 256, 256, 0, stream>>>(dst, deg, E);
    scan_local<<<nbScan, 256, 0, stream>>>(deg, locincl, bsum, N);
    scan_bsum<<<1, 256, 0, stream>>>(bsum, nbScan);
    scan_final<<<nbScan, 256, 0, stream>>>(deg, locincl, bsum, rowptr, cursor, N, E);
    scatter_kernel<<<(E + 255) / 256, 256, 0, stream>>>(src, dst, cursor, esrc, E);

    // ---- weight transpose + split ----
    wtrans<<<(256 * 128 + 255) / 256, 256, 0, stream>>>(enc_w2, nullptr, 128, 128, 256, wtE_hi, wtE_lo);
    wtrans<<<(256 * 512 + 255) / 256, 256, 0, stream>>>(s1_wl, s1_wr, 256, 512, 256, wtS1_hi, wtS1_lo);
    wtrans<<<(256 * 512 + 255) / 256, 256, 0, stream>>>(s2_wl, s2_wr, 256, 512, 256, wtS2_hi, wtS2_lo);
    wtrans<<<(128 * 256 + 255) / 256, 256, 0, stream>>>(ro_w1, nullptr, 256, 256, 128, wtR_hi, wtR_lo);

    // ---- encoder ----
    lin_enc1<IN_DIM, 128, 8><<<nb8, 128, 0, stream>>>(x, enc_w1, enc_b1, h0_hi, h0_lo, N);
    gemm_mfma<128, 0, true, true, true><<<dim3(gx, 2), 256, 0, stream>>>(
        h0_hi, h0_lo, nullptr, nullptr, wtE_hi, wtE_lo, enc_b2, f32buf, hA_hi, hA_lo, N, 256);

    // ---- SAGE 1 ----
    agg_csr<<<N, 256, 0, stream>>>(f32buf, rowptr, esrc, m_hi, m_lo, N);
    gemm_mfma<512, 1, true, true, true><<<dim3(gx, 2), 256, 0, stream>>>(
        m_hi, m_lo, hA_hi, hA_lo, wtS1_hi, wtS1_lo, s1_bl, f32buf, hB_hi, hB_lo, N, 256);

    // ---- SAGE 2 ----
    agg_csr<<<N, 256, 0, stream>>>(f32buf, rowptr, esrc, m_hi, m_lo, N);
    gemm_mfma<512, 1, false, true, true><<<dim3(gx, 2), 256, 0, stream>>>(
        m_hi, m_lo, hB_hi, hB_lo, wtS2_hi, wtS2_lo, s2_bl, nullptr, hA_hi, hA_lo, N, 256);

    // ---- readout ----
    gemm_mfma<256, 0, true, false, true><<<dim3(gx, 1), 256, 0, stream>>>(
        hA_hi, hA_lo, nullptr, nullptr, wtR_hi, wtR_lo, ro_b1, f32buf, nullptr, nullptr, N, 128);
    lin_final<<<(N * OUT_DIM + 255) / 256, 256, 0, stream>>>(f32buf, ro_w2, ro_b2, out, N);
}

// Round 6
// 445.359 us; speedup vs baseline: 3.5988x; 1.0332x over previous
//
#include <hip/hip_runtime.h>
#include <hip/hip_bf16.h>

#define N_NODES 50000
#define N_EDGES 400000
#define IN_DIM 24
#define HID 256
#define OUT_DIM 12

typedef __attribute__((ext_vector_type(8))) short short8;
typedef __attribute__((ext_vector_type(4))) float f32x4;

// async global->LDS, 16 bytes per lane (dest must be linear: base + lane*16 per wave)
__device__ __forceinline__ void gload_lds16(const void* g, void* l) {
    typedef __attribute__((address_space(3))) unsigned int u32_lds;
    typedef const __attribute__((address_space(1))) unsigned int u32_glb;
    __builtin_amdgcn_global_load_lds((u32_glb*)(unsigned long long)g,
                                     (u32_lds*)(unsigned int)(unsigned long long)l,
                                     16, 0, 0);
}

__device__ __forceinline__ void split_store(float v, __hip_bfloat16* hi, __hip_bfloat16* lo, size_t o) {
    __hip_bfloat16 h = __float2bfloat16(v);
    hi[o] = h;
    lo[o] = __float2bfloat16(v - __bfloat162float(h));
}

// ---------------- encoder layer 1 (K=24, f32 compute, bf16 hi/lo out) ----------------
template<int K, int M, int ROWS>
__global__ __launch_bounds__(M) void lin_enc1(const float* __restrict__ X,
                                              const float* __restrict__ W,
                                              const float* __restrict__ b,
                                              __hip_bfloat16* __restrict__ Yhi,
                                              __hip_bfloat16* __restrict__ Ylo, int N) {
    __shared__ float xs[ROWS][K];
    const int row0 = blockIdx.x * ROWS;
    const int tid = threadIdx.x;
    for (int i = tid; i < ROWS * K; i += M) {
        int r = i / K, k = i - r * K;
        int gr = row0 + r;
        xs[r][k] = (gr < N) ? X[(long long)gr * K + k] : 0.f;
    }
    __syncthreads();
    const int j = tid;
    float acc[ROWS];
    float bj = b[j];
#pragma unroll
    for (int r = 0; r < ROWS; ++r) acc[r] = bj;
    for (int k = 0; k < K; ++k) {
        float w = W[k * M + j];
#pragma unroll
        for (int r = 0; r < ROWS; ++r) acc[r] = fmaf(xs[r][k], w, acc[r]);
    }
#pragma unroll
    for (int r = 0; r < ROWS; ++r) {
        int gr = row0 + r;
        if (gr < N) {
            float v = fmaxf(acc[r], 0.f);
            split_store(v, Yhi, Ylo, (size_t)gr * M + j);
        }
    }
}

// ---------------- weight transpose + hi/lo split: Wt[j][k] = W[k][j] ----------------
__global__ void wtrans(const float* __restrict__ W1, const float* __restrict__ W2,
                       int K1, int K, int M,
                       __hip_bfloat16* __restrict__ Whi, __hip_bfloat16* __restrict__ Wlo) {
    int idx = blockIdx.x * blockDim.x + threadIdx.x;
    if (idx >= M * K) return;
    int j = idx / K, k = idx - j * K;
    float v = (k < K1) ? W1[(size_t)k * M + j] : W2[(size_t)(k - K1) * M + j];
    split_store(v, Whi, Wlo, idx);
}

// ---------------- MFMA split-bf16 GEMM ----------------
// MODE 0: X rows from (Ahi,Alo) [N][K]
// MODE 1: k<HID from (Ahi,Alo) [N][HID] (mean), else (A2hi,A2lo) [N][HID] (h)
template<int K, int MODE, bool WF32, bool WBF16, bool RELU>
__global__ __launch_bounds__(256, 4) void gemm_mfma(
    const __hip_bfloat16* __restrict__ Ahi, const __hip_bfloat16* __restrict__ Alo,
    const __hip_bfloat16* __restrict__ A2hi, const __hip_bfloat16* __restrict__ A2lo,
    const __hip_bfloat16* __restrict__ Whi, const __hip_bfloat16* __restrict__ Wlo,
    const float* __restrict__ bias,
    float* __restrict__ Yf, __hip_bfloat16* __restrict__ Yhi, __hip_bfloat16* __restrict__ Ylo,
    int N, int M) {
    __shared__ __align__(16) short lds[4][128 * 32];  // 0=Ahi 1=Alo 2=Bhi 3=Blo, [row][k]
    const int tid = threadIdx.x;
    const int r0 = blockIdx.x * 128;
    const int j0 = blockIdx.y * 128;
    const int w = tid >> 6, lane = tid & 63;
    const int wr = w >> 1, wc = w & 1;
    const int lrow = lane & 15, lg = lane >> 4;

    f32x4 acc[4][4] = {};

    const int crow = tid >> 2;   // staging row 0..63 (+64 second pass)
    const int cg = tid & 3;      // 16B chunk within 64B row

    for (int kc = 0; kc < K; kc += 32) {
        __syncthreads();
        // ---- stage A tiles ----
        const __hip_bfloat16 *pah, *pal;
        int ka, KA;
        if (MODE == 1) {
            KA = HID;
            if (kc >= HID) { pah = A2hi; pal = A2lo; ka = kc - HID; }
            else           { pah = Ahi;  pal = Alo;  ka = kc; }
        } else {
            KA = K; pah = Ahi; pal = Alo; ka = kc;
        }
#pragma unroll
        for (int it = 0; it < 2; ++it) {
            int row = crow + it * 64;
            int gr = r0 + row; if (gr > N - 1) gr = N - 1;
            size_t go = (size_t)gr * KA + ka + cg * 8;
            int lo_off = (row * 4 + cg) * 8;
            gload_lds16(pah + go, &lds[0][lo_off]);
            gload_lds16(pal + go, &lds[1][lo_off]);
        }
        // ---- stage B tiles (Wt rows = output cols) ----
#pragma unroll
        for (int it = 0; it < 2; ++it) {
            int row = crow + it * 64;
            size_t go = (size_t)(j0 + row) * K + kc + cg * 8;
            int lo_off = (row * 4 + cg) * 8;
            gload_lds16(Whi + go, &lds[2][lo_off]);
            gload_lds16(Wlo + go, &lds[3][lo_off]);
        }
        __syncthreads();

        short8 ah[4], al[4], bh[4], bl[4];
#pragma unroll
        for (int f = 0; f < 4; ++f) {
            int ar = wr * 64 + f * 16 + lrow;
            ah[f] = *(const short8*)&lds[0][ar * 32 + lg * 8];
            al[f] = *(const short8*)&lds[1][ar * 32 + lg * 8];
            int br = wc * 64 + f * 16 + lrow;
            bh[f] = *(const short8*)&lds[2][br * 32 + lg * 8];
            bl[f] = *(const short8*)&lds[3][br * 32 + lg * 8];
        }
#pragma unroll
        for (int fi = 0; fi < 4; ++fi)
#pragma unroll
            for (int fj = 0; fj < 4; ++fj) {
                acc[fi][fj] = __builtin_amdgcn_mfma_f32_16x16x32_bf16(ah[fi], bh[fj], acc[fi][fj], 0, 0, 0);
                acc[fi][fj] = __builtin_amdgcn_mfma_f32_16x16x32_bf16(al[fi], bh[fj], acc[fi][fj], 0, 0, 0);
                acc[fi][fj] = __builtin_amdgcn_mfma_f32_16x16x32_bf16(ah[fi], bl[fj], acc[fi][fj], 0, 0, 0);
            }
    }

    // ---- epilogue: C/D layout col=lane&15, row=(lane>>4)*4+reg ----
#pragma unroll
    for (int fj = 0; fj < 4; ++fj) {
        int ocol = j0 + wc * 64 + fj * 16 + lrow;
        float bv = bias[ocol];
#pragma unroll
        for (int fi = 0; fi < 4; ++fi) {
#pragma unroll
            for (int r = 0; r < 4; ++r) {
                int orow = r0 + wr * 64 + fi * 16 + lg * 4 + r;
                if (orow < N) {
                    float v = acc[fi][fj][r] + bv;
                    if (RELU) v = fmaxf(v, 0.f);
                    size_t o = (size_t)orow * M + ocol;
                    if (WF32) Yf[o] = v;
                    if (WBF16) split_store(v, Yhi, Ylo, o);
                }
            }
        }
    }
}

// ---------------- CSR build ----------------
__global__ void deg_kernel(const int* __restrict__ dst, int* __restrict__ deg, int E) {
    int e = blockIdx.x * blockDim.x + threadIdx.x;
    if (e < E) atomicAdd(&deg[dst[e]], 1);
}

// Stage 1: per-block inclusive scan (256 elems/block) + block total
__global__ __launch_bounds__(256) void scan_local(const int* __restrict__ deg,
                                                  int* __restrict__ locincl,
                                                  int* __restrict__ bsum, int N) {
    const int t = threadIdx.x;
    const int i = blockIdx.x * 256 + t;
    int v = (i < N) ? deg[i] : 0;
    const int lane = t & 63;
    int x = v;
#pragma unroll
    for (int off = 1; off < 64; off <<= 1) {
        int y = __shfl_up(x, off, 64);
        if (lane >= off) x += y;
    }
    __shared__ int wsum[4];
    if (lane == 63) wsum[t >> 6] = x;
    __syncthreads();
    const int wid = t >> 6;
    int add = 0;
    for (int wI = 0; wI < wid; ++wI) add += wsum[wI];
    x += add;
    if (i < N) locincl[i] = x;
    if (t == 255) bsum[blockIdx.x] = x;
}

// Stage 2: exclusive scan of block sums (B <= 256), single block
__global__ __launch_bounds__(256) void scan_bsum(int* __restrict__ bsum, int B) {
    const int t = threadIdx.x;
    int v = (t < B) ? bsum[t] : 0;
    const int lane = t & 63;
    int x = v;
#pragma unroll
    for (int off = 1; off < 64; off <<= 1) {
        int y = __shfl_up(x, off, 64);
        if (lane >= off) x += y;
    }
    __shared__ int wsum[4];
    if (lane == 63) wsum[t >> 6] = x;
    __syncthreads();
    const int wid = t >> 6;
    int add = 0;
    for (int wI = 0; wI < wid; ++wI) add += wsum[wI];
    x += add;
    if (t < B) bsum[t] = x - v;   // exclusive
}

// Stage 3: recombine -> exclusive rowptr + cursor
__global__ __launch_bounds__(256) void scan_final(const int* __restrict__ deg,
                                                  const int* __restrict__ locincl,
                                                  const int* __restrict__ bsum,
                                                  int* __restrict__ rowptr,
                                                  int* __restrict__ cursor, int N, int E) {
    const int i = blockIdx.x * 256 + threadIdx.x;
    if (i < N) {
        int excl = bsum[blockIdx.x] + locincl[i] - deg[i];
        rowptr[i] = excl;
        cursor[i] = excl;
    }
    if (i == 0) rowptr[N] = E;
}

__global__ void scatter_kernel(const int* __restrict__ src, const int* __restrict__ dst,
                               int* __restrict__ cursor, int* __restrict__ esrc, int E) {
    int e = blockIdx.x * blockDim.x + threadIdx.x;
    if (e < E) {
        int pos = atomicAdd(&cursor[dst[e]], 1);
        esrc[pos] = src[e];
    }
}

// ---------------- CSR mean-aggregation: reads h as bf16 hi/lo pair, writes hi/lo ----------------
__global__ __launch_bounds__(256) void agg_csr(const __hip_bfloat16* __restrict__ hhi,
                                               const __hip_bfloat16* __restrict__ hlo,
                                               const int* __restrict__ rowptr,
                                               const int* __restrict__ esrc,
                                               __hip_bfloat16* __restrict__ mhi,
                                               __hip_bfloat16* __restrict__ mlo, int N) {
    __shared__ int sl[256];
    const int n = blockIdx.x;
    const int c = threadIdx.x;
    const int r0 = rowptr[n];
    const int r1 = rowptr[n + 1];
    float acc = 0.f;
    for (int base = r0; base < r1; base += 256) {
        int m = min(256, r1 - base);
        if (c < m) sl[c] = esrc[base + c];
        __syncthreads();
        int i = 0;
        for (; i + 4 <= m; i += 4) {
            long long o0 = (long long)sl[i + 0] * HID + c;
            long long o1 = (long long)sl[i + 1] * HID + c;
            long long o2 = (long long)sl[i + 2] * HID + c;
            long long o3 = (long long)sl[i + 3] * HID + c;
            float a0 = __bfloat162float(hhi[o0]) + __bfloat162float(hlo[o0]);
            float a1 = __bfloat162float(hhi[o1]) + __bfloat162float(hlo[o1]);
            float a2 = __bfloat162float(hhi[o2]) + __bfloat162float(hlo[o2]);
            float a3 = __bfloat162float(hhi[o3]) + __bfloat162float(hlo[o3]);
            acc += (a0 + a1) + (a2 + a3);
        }
        for (; i < m; ++i) {
            long long o = (long long)sl[i] * HID + c;
            acc += __bfloat162float(hhi[o]) + __bfloat162float(hlo[o]);
        }
        __syncthreads();
    }
    float inv = 1.0f / fmaxf((float)(r1 - r0), 1.0f);
    split_store(acc * inv, mhi, mlo, (size_t)n * HID + c);
}

// ---------------- Final linear: out[N,12] = h[N,128] @ W[128,12] + b ----------------
__global__ void lin_final(const float* __restrict__ X, const float* __restrict__ W,
                          const float* __restrict__ b, float* __restrict__ Y, int N) {
    int idx = blockIdx.x * blockDim.x + threadIdx.x;
    if (idx >= N * OUT_DIM) return;
    int row = idx / OUT_DIM;
    int j = idx - row * OUT_DIM;
    float acc = b[j];
#pragma unroll 8
    for (int k = 0; k < 128; ++k)
        acc = fmaf(X[row * 128 + k], W[k * OUT_DIM + j], acc);
    Y[idx] = acc;
}

extern "C" void kernel_launch(void* const* d_in, const int* in_sizes, int n_in,
                              void* d_out, int out_size, void* d_ws, size_t ws_size,
                              hipStream_t stream) {
    const float* x      = (const float*)d_in[0];
    const int*   eidx   = (const int*)d_in[1];
    const float* enc_w1 = (const float*)d_in[2];
    const float* enc_b1 = (const float*)d_in[3];
    const float* enc_w2 = (const float*)d_in[4];
    const float* enc_b2 = (const float*)d_in[5];
    const float* s1_wl  = (const float*)d_in[6];
    const float* s1_bl  = (const float*)d_in[7];
    const float* s1_wr  = (const float*)d_in[8];
    const float* s2_wl  = (const float*)d_in[9];
    const float* s2_bl  = (const float*)d_in[10];
    const float* s2_wr  = (const float*)d_in[11];
    const float* ro_w1  = (const float*)d_in[12];
    const float* ro_b1  = (const float*)d_in[13];
    const float* ro_w2  = (const float*)d_in[14];
    const float* ro_b2  = (const float*)d_in[15];
    float* out = (float*)d_out;

    const int N = N_NODES;
    const int E = N_EDGES;
    const int* src = eidx;
    const int* dst = eidx + E;

    typedef __hip_bfloat16 bf16;
    char* ws = (char*)d_ws;
    size_t off = 0;
    auto alloc = [&](size_t bytes) { void* p = ws + off; off += (bytes + 255) & ~255ULL; return p; };
    int* deg     = (int*)alloc((size_t)N * 4);
    int* rowptr  = (int*)alloc((size_t)(N + 1) * 4);
    int* cursor  = (int*)alloc((size_t)N * 4);
    int* esrc    = (int*)alloc((size_t)E * 4);
    int* locincl = (int*)alloc((size_t)N * 4);
    int* bsum    = (int*)alloc((size_t)256 * 4);
    bf16* wtE_hi = (bf16*)alloc((size_t)256 * 128 * 2);
    bf16* wtE_lo = (bf16*)alloc((size_t)256 * 128 * 2);
    bf16* wtS1_hi = (bf16*)alloc((size_t)256 * 512 * 2);
    bf16* wtS1_lo = (bf16*)alloc((size_t)256 * 512 * 2);
    bf16* wtS2_hi = (bf16*)alloc((size_t)256 * 512 * 2);
    bf16* wtS2_lo = (bf16*)alloc((size_t)256 * 512 * 2);
    bf16* wtR_hi = (bf16*)alloc((size_t)128 * 256 * 2);
    bf16* wtR_lo = (bf16*)alloc((size_t)128 * 256 * 2);
    bf16* h0_hi = (bf16*)alloc((size_t)N * 128 * 2);
    bf16* h0_lo = (bf16*)alloc((size_t)N * 128 * 2);
    float* f32buf = (float*)alloc((size_t)N * 128 * 4);
    bf16* hA_hi = (bf16*)alloc((size_t)N * HID * 2);
    bf16* hA_lo = (bf16*)alloc((size_t)N * HID * 2);
    bf16* hB_hi = (bf16*)alloc((size_t)N * HID * 2);
    bf16* hB_lo = (bf16*)alloc((size_t)N * HID * 2);
    bf16* m_hi = (bf16*)alloc((size_t)N * HID * 2);
    bf16* m_lo = (bf16*)alloc((size_t)N * HID * 2);

    const int nb8 = (N + 7) / 8;
    const int gx = (N + 127) / 128;
    const int nbScan = (N + 255) / 256;

    // ---- CSR build ----
    hipMemsetAsync(deg, 0, (size_t)N * 4, stream);
    deg_kernel<<<(E + 255) / 256, 256, 0, stream>>>(dst, deg, E);
    scan_local<<<nbScan, 256, 0, stream>>>(deg, locincl, bsum, N);
    scan_bsum<<<1, 256, 0, stream>>>(bsum, nbScan);
    scan_final<<<nbScan, 256, 0, stream>>>(deg, locincl, bsum, rowptr, cursor, N, E);
    scatter_kernel<<<(E + 255) / 256, 256, 0, stream>>>(src, dst, cursor, esrc, E);

    // ---- weight transpose + split ----
    wtrans<<<(256 * 128 + 255) / 256, 256, 0, stream>>>(enc_w2, nullptr, 128, 128, 256, wtE_hi, wtE_lo);
    wtrans<<<(256 * 512 + 255) / 256, 256, 0, stream>>>(s1_wl, s1_wr, 256, 512, 256, wtS1_hi, wtS1_lo);
    wtrans<<<(256 * 512 + 255) / 256, 256, 0, stream>>>(s2_wl, s2_wr, 256, 512, 256, wtS2_hi, wtS2_lo);
    wtrans<<<(128 * 256 + 255) / 256, 256, 0, stream>>>(ro_w1, nullptr, 256, 256, 128, wtR_hi, wtR_lo);

    // ---- encoder ----
    lin_enc1<IN_DIM, 128, 8><<<nb8, 128, 0, stream>>>(x, enc_w1, enc_b1, h0_hi, h0_lo, N);
    gemm_mfma<128, 0, false, true, true><<<dim3(gx, 2), 256, 0, stream>>>(
        h0_hi, h0_lo, nullptr, nullptr, wtE_hi, wtE_lo, enc_b2, nullptr, hA_hi, hA_lo, N, 256);

    // ---- SAGE 1 ----
    agg_csr<<<N, 256, 0, stream>>>(hA_hi, hA_lo, rowptr, esrc, m_hi, m_lo, N);
    gemm_mfma<512, 1, false, true, true><<<dim3(gx, 2), 256, 0, stream>>>(
        m_hi, m_lo, hA_hi, hA_lo, wtS1_hi, wtS1_lo, s1_bl, nullptr, hB_hi, hB_lo, N, 256);

    // ---- SAGE 2 ----
    agg_csr<<<N, 256, 0, stream>>>(hB_hi, hB_lo, rowptr, esrc, m_hi, m_lo, N);
    gemm_mfma<512, 1, false, true, true><<<dim3(gx, 2), 256, 0, stream>>>(
        m_hi, m_lo, hB_hi, hB_lo, wtS2_hi, wtS2_lo, s2_bl, nullptr, hA_hi, hA_lo, N, 256);

    // ---- readout ----
    gemm_mfma<256, 0, true, false, true><<<dim3(gx, 1), 256, 0, stream>>>(
        hA_hi, hA_lo, nullptr, nullptr, wtR_hi, wtR_lo, ro_b1, f32buf, nullptr, nullptr, N, 128);
    lin_final<<<(N * OUT_DIM + 255) / 256, 256, 0, stream>>>(f32buf, ro_w2, ro_b2, out, N);
}

// Round 7
// 423.658 us; speedup vs baseline: 3.7831x; 1.0512x over previous
//
#include <hip/hip_runtime.h>
#include <hip/hip_bf16.h>

#define N_NODES 50000
#define N_EDGES 400000
#define IN_DIM 24
#define HID 256
#define OUT_DIM 12

typedef __attribute__((ext_vector_type(8))) short short8;
typedef __attribute__((ext_vector_type(4))) float f32x4;

// async global->LDS, 16 bytes per lane (dest must be linear: base + lane*16 per wave)
__device__ __forceinline__ void gload_lds16(const void* g, void* l) {
    typedef __attribute__((address_space(3))) unsigned int u32_lds;
    typedef const __attribute__((address_space(1))) unsigned int u32_glb;
    __builtin_amdgcn_global_load_lds((u32_glb*)(unsigned long long)g,
                                     (u32_lds*)(unsigned int)(unsigned long long)l,
                                     16, 0, 0);
}

__device__ __forceinline__ void split_store(float v, __hip_bfloat16* hi, __hip_bfloat16* lo, size_t o) {
    __hip_bfloat16 h = __float2bfloat16(v);
    hi[o] = h;
    lo[o] = __float2bfloat16(v - __bfloat162float(h));
}

// ---------------- encoder layer 1 (K=24, f32 compute, bf16 hi/lo out) ----------------
template<int K, int M, int ROWS>
__global__ __launch_bounds__(M) void lin_enc1(const float* __restrict__ X,
                                              const float* __restrict__ W,
                                              const float* __restrict__ b,
                                              __hip_bfloat16* __restrict__ Yhi,
                                              __hip_bfloat16* __restrict__ Ylo, int N) {
    __shared__ float xs[ROWS][K];
    const int row0 = blockIdx.x * ROWS;
    const int tid = threadIdx.x;
    for (int i = tid; i < ROWS * K; i += M) {
        int r = i / K, k = i - r * K;
        int gr = row0 + r;
        xs[r][k] = (gr < N) ? X[(long long)gr * K + k] : 0.f;
    }
    __syncthreads();
    const int j = tid;
    float acc[ROWS];
    float bj = b[j];
#pragma unroll
    for (int r = 0; r < ROWS; ++r) acc[r] = bj;
    for (int k = 0; k < K; ++k) {
        float w = W[k * M + j];
#pragma unroll
        for (int r = 0; r < ROWS; ++r) acc[r] = fmaf(xs[r][k], w, acc[r]);
    }
#pragma unroll
    for (int r = 0; r < ROWS; ++r) {
        int gr = row0 + r;
        if (gr < N) {
            float v = fmaxf(acc[r], 0.f);
            split_store(v, Yhi, Ylo, (size_t)gr * M + j);
        }
    }
}

// ---------------- weight transpose + hi/lo split: Wt[j][k] = W[k][j] ----------------
__global__ void wtrans(const float* __restrict__ W1, const float* __restrict__ W2,
                       int K1, int K, int M,
                       __hip_bfloat16* __restrict__ Whi, __hip_bfloat16* __restrict__ Wlo) {
    int idx = blockIdx.x * blockDim.x + threadIdx.x;
    if (idx >= M * K) return;
    int j = idx / K, k = idx - j * K;
    float v = (k < K1) ? W1[(size_t)k * M + j] : W2[(size_t)(k - K1) * M + j];
    split_store(v, Whi, Wlo, idx);
}

// ---------------- MFMA split-bf16 GEMM ----------------
// Block tile 128 x BN, BK=32. Waves: BN*2/64, wave tile 64x64 (4x4 frags 16x16x32).
// MODE 0: X rows from (Ahi,Alo) [N][K]
// MODE 1: k<HID from (Ahi,Alo) [N][HID] (mean), else (A2hi,A2lo) [N][HID] (h)
template<int K, int MODE, int BN, bool WF32, bool WBF16, bool RELU>
__global__ __launch_bounds__(BN * 2, 4) void gemm_mfma(
    const __hip_bfloat16* __restrict__ Ahi, const __hip_bfloat16* __restrict__ Alo,
    const __hip_bfloat16* __restrict__ A2hi, const __hip_bfloat16* __restrict__ A2lo,
    const __hip_bfloat16* __restrict__ Whi, const __hip_bfloat16* __restrict__ Wlo,
    const float* __restrict__ bias,
    float* __restrict__ Yf, __hip_bfloat16* __restrict__ Yhi, __hip_bfloat16* __restrict__ Ylo,
    int N, int M) {
    constexpr int NT = BN * 2;          // threads
    constexpr int NWC = BN / 64;        // wave columns
    __shared__ __align__(16) short ldsAhi[128 * 32];
    __shared__ __align__(16) short ldsAlo[128 * 32];
    __shared__ __align__(16) short ldsBhi[BN * 32];
    __shared__ __align__(16) short ldsBlo[BN * 32];
    const int tid = threadIdx.x;
    const int r0 = blockIdx.x * 128;
    const int j0 = blockIdx.y * BN;
    const int w = tid >> 6, lane = tid & 63;
    const int wr = w / NWC, wc = w % NWC;
    const int lrow = lane & 15, lg = lane >> 4;

    f32x4 acc[4][4] = {};

    for (int kc = 0; kc < K; kc += 32) {
        __syncthreads();
        // ---- stage A tile (128 x 32, hi+lo) ----
        const __hip_bfloat16 *pah, *pal;
        int ka, KA;
        if (MODE == 1) {
            KA = HID;
            if (kc >= HID) { pah = A2hi; pal = A2lo; ka = kc - HID; }
            else           { pah = Ahi;  pal = Alo;  ka = kc; }
        } else {
            KA = K; pah = Ahi; pal = Alo; ka = kc;
        }
#pragma unroll
        for (int c = tid; c < 512; c += NT) {
            int row = c >> 2, cg = c & 3;
            int gr = r0 + row; if (gr > N - 1) gr = N - 1;
            size_t go = (size_t)gr * KA + ka + cg * 8;
            gload_lds16(pah + go, (char*)ldsAhi + (size_t)c * 16);
            gload_lds16(pal + go, (char*)ldsAlo + (size_t)c * 16);
        }
        // ---- stage B tile (BN x 32, hi+lo) ----
#pragma unroll
        for (int c = tid; c < BN * 4; c += NT) {
            int wrow = c >> 2, cg = c & 3;
            size_t go = (size_t)(j0 + wrow) * K + kc + cg * 8;
            gload_lds16(Whi + go, (char*)ldsBhi + (size_t)c * 16);
            gload_lds16(Wlo + go, (char*)ldsBlo + (size_t)c * 16);
        }
        __syncthreads();

        short8 ah[4], al[4], bh[4], bl[4];
#pragma unroll
        for (int f = 0; f < 4; ++f) {
            int ar = wr * 64 + f * 16 + lrow;
            ah[f] = *(const short8*)&ldsAhi[ar * 32 + lg * 8];
            al[f] = *(const short8*)&ldsAlo[ar * 32 + lg * 8];
            int br = wc * 64 + f * 16 + lrow;
            bh[f] = *(const short8*)&ldsBhi[br * 32 + lg * 8];
            bl[f] = *(const short8*)&ldsBlo[br * 32 + lg * 8];
        }
#pragma unroll
        for (int fi = 0; fi < 4; ++fi)
#pragma unroll
            for (int fj = 0; fj < 4; ++fj) {
                acc[fi][fj] = __builtin_amdgcn_mfma_f32_16x16x32_bf16(ah[fi], bh[fj], acc[fi][fj], 0, 0, 0);
                acc[fi][fj] = __builtin_amdgcn_mfma_f32_16x16x32_bf16(al[fi], bh[fj], acc[fi][fj], 0, 0, 0);
                acc[fi][fj] = __builtin_amdgcn_mfma_f32_16x16x32_bf16(ah[fi], bl[fj], acc[fi][fj], 0, 0, 0);
            }
    }

    // ---- epilogue: C/D layout col=lane&15, row=(lane>>4)*4+reg ----
#pragma unroll
    for (int fj = 0; fj < 4; ++fj) {
        int ocol = j0 + wc * 64 + fj * 16 + lrow;
        float bv = bias[ocol];
#pragma unroll
        for (int fi = 0; fi < 4; ++fi) {
#pragma unroll
            for (int r = 0; r < 4; ++r) {
                int orow = r0 + wr * 64 + fi * 16 + lg * 4 + r;
                if (orow < N) {
                    float v = acc[fi][fj][r] + bv;
                    if (RELU) v = fmaxf(v, 0.f);
                    size_t o = (size_t)orow * M + ocol;
                    if (WF32) Yf[o] = v;
                    if (WBF16) split_store(v, Yhi, Ylo, o);
                }
            }
        }
    }
}

// ---------------- CSR build ----------------
__global__ void deg_kernel(const int* __restrict__ dst, int* __restrict__ deg, int E) {
    int e = blockIdx.x * blockDim.x + threadIdx.x;
    if (e < E) atomicAdd(&deg[dst[e]], 1);
}

// Stage 1: per-block inclusive scan (256 elems/block) + block total
__global__ __launch_bounds__(256) void scan_local(const int* __restrict__ deg,
                                                  int* __restrict__ locincl,
                                                  int* __restrict__ bsum, int N) {
    const int t = threadIdx.x;
    const int i = blockIdx.x * 256 + t;
    int v = (i < N) ? deg[i] : 0;
    const int lane = t & 63;
    int x = v;
#pragma unroll
    for (int off = 1; off < 64; off <<= 1) {
        int y = __shfl_up(x, off, 64);
        if (lane >= off) x += y;
    }
    __shared__ int wsum[4];
    if (lane == 63) wsum[t >> 6] = x;
    __syncthreads();
    const int wid = t >> 6;
    int add = 0;
    for (int wI = 0; wI < wid; ++wI) add += wsum[wI];
    x += add;
    if (i < N) locincl[i] = x;
    if (t == 255) bsum[blockIdx.x] = x;
}

// Stage 2: exclusive scan of block sums (B <= 256), single block
__global__ __launch_bounds__(256) void scan_bsum(int* __restrict__ bsum, int B) {
    const int t = threadIdx.x;
    int v = (t < B) ? bsum[t] : 0;
    const int lane = t & 63;
    int x = v;
#pragma unroll
    for (int off = 1; off < 64; off <<= 1) {
        int y = __shfl_up(x, off, 64);
        if (lane >= off) x += y;
    }
    __shared__ int wsum[4];
    if (lane == 63) wsum[t >> 6] = x;
    __syncthreads();
    const int wid = t >> 6;
    int add = 0;
    for (int wI = 0; wI < wid; ++wI) add += wsum[wI];
    x += add;
    if (t < B) bsum[t] = x - v;   // exclusive
}

// Stage 3: recombine -> exclusive rowptr + cursor
__global__ __launch_bounds__(256) void scan_final(const int* __restrict__ deg,
                                                  const int* __restrict__ locincl,
                                                  const int* __restrict__ bsum,
                                                  int* __restrict__ rowptr,
                                                  int* __restrict__ cursor, int N, int E) {
    const int i = blockIdx.x * 256 + threadIdx.x;
    if (i < N) {
        int excl = bsum[blockIdx.x] + locincl[i] - deg[i];
        rowptr[i] = excl;
        cursor[i] = excl;
    }
    if (i == 0) rowptr[N] = E;
}

__global__ void scatter_kernel(const int* __restrict__ src, const int* __restrict__ dst,
                               int* __restrict__ cursor, int* __restrict__ esrc, int E) {
    int e = blockIdx.x * blockDim.x + threadIdx.x;
    if (e < E) {
        int pos = atomicAdd(&cursor[dst[e]], 1);
        esrc[pos] = src[e];
    }
}

// ---------------- CSR mean-aggregation: reads h as bf16 hi/lo pair, writes hi/lo ----------------
__global__ __launch_bounds__(256) void agg_csr(const __hip_bfloat16* __restrict__ hhi,
                                               const __hip_bfloat16* __restrict__ hlo,
                                               const int* __restrict__ rowptr,
                                               const int* __restrict__ esrc,
                                               __hip_bfloat16* __restrict__ mhi,
                                               __hip_bfloat16* __restrict__ mlo, int N) {
    __shared__ int sl[256];
    const int n = blockIdx.x;
    const int c = threadIdx.x;
    const int r0 = rowptr[n];
    const int r1 = rowptr[n + 1];
    float acc = 0.f;
    for (int base = r0; base < r1; base += 256) {
        int m = min(256, r1 - base);
        if (c < m) sl[c] = esrc[base + c];
        __syncthreads();
        int i = 0;
        for (; i + 4 <= m; i += 4) {
            long long o0 = (long long)sl[i + 0] * HID + c;
            long long o1 = (long long)sl[i + 1] * HID + c;
            long long o2 = (long long)sl[i + 2] * HID + c;
            long long o3 = (long long)sl[i + 3] * HID + c;
            float a0 = __bfloat162float(hhi[o0]) + __bfloat162float(hlo[o0]);
            float a1 = __bfloat162float(hhi[o1]) + __bfloat162float(hlo[o1]);
            float a2 = __bfloat162float(hhi[o2]) + __bfloat162float(hlo[o2]);
            float a3 = __bfloat162float(hhi[o3]) + __bfloat162float(hlo[o3]);
            acc += (a0 + a1) + (a2 + a3);
        }
        for (; i < m; ++i) {
            long long o = (long long)sl[i] * HID + c;
            acc += __bfloat162float(hhi[o]) + __bfloat162float(hlo[o]);
        }
        __syncthreads();
    }
    float inv = 1.0f / fmaxf((float)(r1 - r0), 1.0f);
    split_store(acc * inv, mhi, mlo, (size_t)n * HID + c);
}

// ---------------- Final linear: out[N,12] = h[N,128] @ W[128,12] + b ----------------
__global__ void lin_final(const float* __restrict__ X, const float* __restrict__ W,
                          const float* __restrict__ b, float* __restrict__ Y, int N) {
    int idx = blockIdx.x * blockDim.x + threadIdx.x;
    if (idx >= N * OUT_DIM) return;
    int row = idx / OUT_DIM;
    int j = idx - row * OUT_DIM;
    float acc = b[j];
#pragma unroll 8
    for (int k = 0; k < 128; ++k)
        acc = fmaf(X[row * 128 + k], W[k * OUT_DIM + j], acc);
    Y[idx] = acc;
}

extern "C" void kernel_launch(void* const* d_in, const int* in_sizes, int n_in,
                              void* d_out, int out_size, void* d_ws, size_t ws_size,
                              hipStream_t stream) {
    const float* x      = (const float*)d_in[0];
    const int*   eidx   = (const int*)d_in[1];
    const float* enc_w1 = (const float*)d_in[2];
    const float* enc_b1 = (const float*)d_in[3];
    const float* enc_w2 = (const float*)d_in[4];
    const float* enc_b2 = (const float*)d_in[5];
    const float* s1_wl  = (const float*)d_in[6];
    const float* s1_bl  = (const float*)d_in[7];
    const float* s1_wr  = (const float*)d_in[8];
    const float* s2_wl  = (const float*)d_in[9];
    const float* s2_bl  = (const float*)d_in[10];
    const float* s2_wr  = (const float*)d_in[11];
    const float* ro_w1  = (const float*)d_in[12];
    const float* ro_b1  = (const float*)d_in[13];
    const float* ro_w2  = (const float*)d_in[14];
    const float* ro_b2  = (const float*)d_in[15];
    float* out = (float*)d_out;

    const int N = N_NODES;
    const int E = N_EDGES;
    const int* src = eidx;
    const int* dst = eidx + E;

    typedef __hip_bfloat16 bf16;
    char* ws = (char*)d_ws;
    size_t off = 0;
    auto alloc = [&](size_t bytes) { void* p = ws + off; off += (bytes + 255) & ~255ULL; return p; };
    int* deg     = (int*)alloc((size_t)N * 4);
    int* rowptr  = (int*)alloc((size_t)(N + 1) * 4);
    int* cursor  = (int*)alloc((size_t)N * 4);
    int* esrc    = (int*)alloc((size_t)E * 4);
    int* locincl = (int*)alloc((size_t)N * 4);
    int* bsum    = (int*)alloc((size_t)256 * 4);
    bf16* wtE_hi = (bf16*)alloc((size_t)256 * 128 * 2);
    bf16* wtE_lo = (bf16*)alloc((size_t)256 * 128 * 2);
    bf16* wtS1_hi = (bf16*)alloc((size_t)256 * 512 * 2);
    bf16* wtS1_lo = (bf16*)alloc((size_t)256 * 512 * 2);
    bf16* wtS2_hi = (bf16*)alloc((size_t)256 * 512 * 2);
    bf16* wtS2_lo = (bf16*)alloc((size_t)256 * 512 * 2);
    bf16* wtR_hi = (bf16*)alloc((size_t)128 * 256 * 2);
    bf16* wtR_lo = (bf16*)alloc((size_t)128 * 256 * 2);
    bf16* h0_hi = (bf16*)alloc((size_t)N * 128 * 2);
    bf16* h0_lo = (bf16*)alloc((size_t)N * 128 * 2);
    float* f32buf = (float*)alloc((size_t)N * 128 * 4);
    bf16* hA_hi = (bf16*)alloc((size_t)N * HID * 2);
    bf16* hA_lo = (bf16*)alloc((size_t)N * HID * 2);
    bf16* hB_hi = (bf16*)alloc((size_t)N * HID * 2);
    bf16* hB_lo = (bf16*)alloc((size_t)N * HID * 2);
    bf16* m_hi = (bf16*)alloc((size_t)N * HID * 2);
    bf16* m_lo = (bf16*)alloc((size_t)N * HID * 2);

    const int nb8 = (N + 7) / 8;
    const int gx = (N + 127) / 128;
    const int nbScan = (N + 255) / 256;

    // ---- CSR build ----
    hipMemsetAsync(deg, 0, (size_t)N * 4, stream);
    deg_kernel<<<(E + 255) / 256, 256, 0, stream>>>(dst, deg, E);
    scan_local<<<nbScan, 256, 0, stream>>>(deg, locincl, bsum, N);
    scan_bsum<<<1, 256, 0, stream>>>(bsum, nbScan);
    scan_final<<<nbScan, 256, 0, stream>>>(deg, locincl, bsum, rowptr, cursor, N, E);
    scatter_kernel<<<(E + 255) / 256, 256, 0, stream>>>(src, dst, cursor, esrc, E);

    // ---- weight transpose + split ----
    wtrans<<<(256 * 128 + 255) / 256, 256, 0, stream>>>(enc_w2, nullptr, 128, 128, 256, wtE_hi, wtE_lo);
    wtrans<<<(256 * 512 + 255) / 256, 256, 0, stream>>>(s1_wl, s1_wr, 256, 512, 256, wtS1_hi, wtS1_lo);
    wtrans<<<(256 * 512 + 255) / 256, 256, 0, stream>>>(s2_wl, s2_wr, 256, 512, 256, wtS2_hi, wtS2_lo);
    wtrans<<<(128 * 256 + 255) / 256, 256, 0, stream>>>(ro_w1, nullptr, 256, 256, 128, wtR_hi, wtR_lo);

    // ---- encoder ----
    lin_enc1<IN_DIM, 128, 8><<<nb8, 128, 0, stream>>>(x, enc_w1, enc_b1, h0_hi, h0_lo, N);
    gemm_mfma<128, 0, 256, false, true, true><<<dim3(gx, 1), 512, 0, stream>>>(
        h0_hi, h0_lo, nullptr, nullptr, wtE_hi, wtE_lo, enc_b2, nullptr, hA_hi, hA_lo, N, 256);

    // ---- SAGE 1 ----
    agg_csr<<<N, 256, 0, stream>>>(hA_hi, hA_lo, rowptr, esrc, m_hi, m_lo, N);
    gemm_mfma<512, 1, 256, false, true, true><<<dim3(gx, 1), 512, 0, stream>>>(
        m_hi, m_lo, hA_hi, hA_lo, wtS1_hi, wtS1_lo, s1_bl, nullptr, hB_hi, hB_lo, N, 256);

    // ---- SAGE 2 ----
    agg_csr<<<N, 256, 0, stream>>>(hB_hi, hB_lo, rowptr, esrc, m_hi, m_lo, N);
    gemm_mfma<512, 1, 256, false, true, true><<<dim3(gx, 1), 512, 0, stream>>>(
        m_hi, m_lo, hB_hi, hB_lo, wtS2_hi, wtS2_lo, s2_bl, nullptr, hA_hi, hA_lo, N, 256);

    // ---- readout ----
    gemm_mfma<256, 0, 128, true, false, true><<<dim3(gx, 1), 256, 0, stream>>>(
        hA_hi, hA_lo, nullptr, nullptr, wtR_hi, wtR_lo, ro_b1, f32buf, nullptr, nullptr, N, 128);
    lin_final<<<(N * OUT_DIM + 255) / 256, 256, 0, stream>>>(f32buf, ro_w2, ro_b2, out, N);
}

// Round 8
// 339.600 us; speedup vs baseline: 4.7195x; 1.2475x over previous
//
#include <hip/hip_runtime.h>
#include <hip/hip_bf16.h>

#define N_NODES 50000
#define N_EDGES 400000
#define IN_DIM 24
#define HID 256
#define OUT_DIM 12

typedef _Float16 fp16_t;
typedef __attribute__((ext_vector_type(8))) _Float16 half8;
typedef __attribute__((ext_vector_type(4))) float f32x4;

// async global->LDS, 16 bytes per lane (dest must be linear: base + lane*16 per wave)
__device__ __forceinline__ void gload_lds16(const void* g, void* l) {
    typedef __attribute__((address_space(3))) unsigned int u32_lds;
    typedef const __attribute__((address_space(1))) unsigned int u32_glb;
    __builtin_amdgcn_global_load_lds((u32_glb*)(unsigned long long)g,
                                     (u32_lds*)(unsigned int)(unsigned long long)l,
                                     16, 0, 0);
}

// ---------------- encoder layer 1 (K=24, f32 compute, fp16 out) ----------------
template<int K, int M, int ROWS>
__global__ __launch_bounds__(M) void lin_enc1(const float* __restrict__ X,
                                              const float* __restrict__ W,
                                              const float* __restrict__ b,
                                              fp16_t* __restrict__ Y, int N) {
    __shared__ float xs[ROWS][K];
    const int row0 = blockIdx.x * ROWS;
    const int tid = threadIdx.x;
    for (int i = tid; i < ROWS * K; i += M) {
        int r = i / K, k = i - r * K;
        int gr = row0 + r;
        xs[r][k] = (gr < N) ? X[(long long)gr * K + k] : 0.f;
    }
    __syncthreads();
    const int j = tid;
    float acc[ROWS];
    float bj = b[j];
#pragma unroll
    for (int r = 0; r < ROWS; ++r) acc[r] = bj;
    for (int k = 0; k < K; ++k) {
        float w = W[k * M + j];
#pragma unroll
        for (int r = 0; r < ROWS; ++r) acc[r] = fmaf(xs[r][k], w, acc[r]);
    }
#pragma unroll
    for (int r = 0; r < ROWS; ++r) {
        int gr = row0 + r;
        if (gr < N) {
            float v = fmaxf(acc[r], 0.f);
            Y[(size_t)gr * M + j] = (fp16_t)v;
        }
    }
}

// ---------------- weight transpose + fp16 hi/lo split: Wt[j][k] = W[k][j] ----------------
__global__ void wtrans(const float* __restrict__ W1, const float* __restrict__ W2,
                       int K1, int K, int M,
                       fp16_t* __restrict__ Whi, fp16_t* __restrict__ Wlo) {
    int idx = blockIdx.x * blockDim.x + threadIdx.x;
    if (idx >= M * K) return;
    int j = idx / K, k = idx - j * K;
    float v = (k < K1) ? W1[(size_t)k * M + j] : W2[(size_t)(k - K1) * M + j];
    fp16_t h = (fp16_t)v;
    Whi[idx] = h;
    Wlo[idx] = (fp16_t)(v - (float)h);
}

// ---------------- MFMA fp16 GEMM: Y = relu?(A @ (Whi+Wlo)^T + b) ----------------
// Block tile 128 x BN, BK=32. Waves: BN*2/64, wave tile 64x64 (4x4 frags 16x16x32).
// MODE 0: A rows from A [N][K]
// MODE 1: k<HID from A [N][HID] (mean), else A2 [N][HID] (h)
template<int K, int MODE, int BN, bool WF32, bool WH16, bool RELU>
__global__ __launch_bounds__(BN * 2, 4) void gemm_mfma(
    const fp16_t* __restrict__ A, const fp16_t* __restrict__ A2,
    const fp16_t* __restrict__ Whi, const fp16_t* __restrict__ Wlo,
    const float* __restrict__ bias,
    float* __restrict__ Yf, fp16_t* __restrict__ Yh,
    int N, int M) {
    constexpr int NT = BN * 2;          // threads
    constexpr int NWC = BN / 64;        // wave columns
    __shared__ __align__(16) fp16_t ldsA[128 * 32];
    __shared__ __align__(16) fp16_t ldsBh[BN * 32];
    __shared__ __align__(16) fp16_t ldsBl[BN * 32];
    const int tid = threadIdx.x;
    const int r0 = blockIdx.x * 128;
    const int j0 = blockIdx.y * BN;
    const int w = tid >> 6, lane = tid & 63;
    const int wr = w / NWC, wc = w % NWC;
    const int lrow = lane & 15, lg = lane >> 4;

    f32x4 acc[4][4] = {};

    for (int kc = 0; kc < K; kc += 32) {
        __syncthreads();
        // ---- stage A tile (128 x 32) : 512 x 16B chunks ----
        const fp16_t* pa;
        int ka, KA;
        if (MODE == 1) {
            KA = HID;
            if (kc >= HID) { pa = A2; ka = kc - HID; }
            else           { pa = A;  ka = kc; }
        } else {
            KA = K; pa = A; ka = kc;
        }
#pragma unroll
        for (int c = tid; c < 512; c += NT) {
            int row = c >> 2, cg = c & 3;
            int gr = r0 + row; if (gr > N - 1) gr = N - 1;
            size_t go = (size_t)gr * KA + ka + cg * 8;
            gload_lds16(pa + go, (char*)ldsA + (size_t)c * 16);
        }
        // ---- stage B tiles (BN x 32, hi+lo) : BN*4 x 16B chunks each ----
#pragma unroll
        for (int c = tid; c < BN * 4; c += NT) {
            int wrow = c >> 2, cg = c & 3;
            size_t go = (size_t)(j0 + wrow) * K + kc + cg * 8;
            gload_lds16(Whi + go, (char*)ldsBh + (size_t)c * 16);
            gload_lds16(Wlo + go, (char*)ldsBl + (size_t)c * 16);
        }
        __syncthreads();

        half8 a[4], bh[4], bl[4];
#pragma unroll
        for (int f = 0; f < 4; ++f) {
            int ar = wr * 64 + f * 16 + lrow;
            a[f] = *(const half8*)&ldsA[ar * 32 + lg * 8];
            int br = wc * 64 + f * 16 + lrow;
            bh[f] = *(const half8*)&ldsBh[br * 32 + lg * 8];
            bl[f] = *(const half8*)&ldsBl[br * 32 + lg * 8];
        }
#pragma unroll
        for (int fi = 0; fi < 4; ++fi)
#pragma unroll
            for (int fj = 0; fj < 4; ++fj) {
                acc[fi][fj] = __builtin_amdgcn_mfma_f32_16x16x32_f16(a[fi], bh[fj], acc[fi][fj], 0, 0, 0);
                acc[fi][fj] = __builtin_amdgcn_mfma_f32_16x16x32_f16(a[fi], bl[fj], acc[fi][fj], 0, 0, 0);
            }
    }

    // ---- epilogue: C/D layout col=lane&15, row=(lane>>4)*4+reg ----
#pragma unroll
    for (int fj = 0; fj < 4; ++fj) {
        int ocol = j0 + wc * 64 + fj * 16 + lrow;
        float bv = bias[ocol];
#pragma unroll
        for (int fi = 0; fi < 4; ++fi) {
#pragma unroll
            for (int r = 0; r < 4; ++r) {
                int orow = r0 + wr * 64 + fi * 16 + lg * 4 + r;
                if (orow < N) {
                    float v = acc[fi][fj][r] + bv;
                    if (RELU) v = fmaxf(v, 0.f);
                    size_t o = (size_t)orow * M + ocol;
                    if (WF32) Yf[o] = v;
                    if (WH16) Yh[o] = (fp16_t)v;
                }
            }
        }
    }
}

// ---------------- CSR build ----------------
__global__ void deg_kernel(const int* __restrict__ dst, int* __restrict__ deg, int E) {
    int e = blockIdx.x * blockDim.x + threadIdx.x;
    if (e < E) atomicAdd(&deg[dst[e]], 1);
}

// Stage 1: per-block inclusive scan (256 elems/block) + block total
__global__ __launch_bounds__(256) void scan_local(const int* __restrict__ deg,
                                                  int* __restrict__ locincl,
                                                  int* __restrict__ bsum, int N) {
    const int t = threadIdx.x;
    const int i = blockIdx.x * 256 + t;
    int v = (i < N) ? deg[i] : 0;
    const int lane = t & 63;
    int x = v;
#pragma unroll
    for (int off = 1; off < 64; off <<= 1) {
        int y = __shfl_up(x, off, 64);
        if (lane >= off) x += y;
    }
    __shared__ int wsum[4];
    if (lane == 63) wsum[t >> 6] = x;
    __syncthreads();
    const int wid = t >> 6;
    int add = 0;
    for (int wI = 0; wI < wid; ++wI) add += wsum[wI];
    x += add;
    if (i < N) locincl[i] = x;
    if (t == 255) bsum[blockIdx.x] = x;
}

// Stage 2: exclusive scan of block sums (B <= 256), single block
__global__ __launch_bounds__(256) void scan_bsum(int* __restrict__ bsum, int B) {
    const int t = threadIdx.x;
    int v = (t < B) ? bsum[t] : 0;
    const int lane = t & 63;
    int x = v;
#pragma unroll
    for (int off = 1; off < 64; off <<= 1) {
        int y = __shfl_up(x, off, 64);
        if (lane >= off) x += y;
    }
    __shared__ int wsum[4];
    if (lane == 63) wsum[t >> 6] = x;
    __syncthreads();
    const int wid = t >> 6;
    int add = 0;
    for (int wI = 0; wI < wid; ++wI) add += wsum[wI];
    x += add;
    if (t < B) bsum[t] = x - v;   // exclusive
}

// Stage 3: recombine -> exclusive rowptr + cursor
__global__ __launch_bounds__(256) void scan_final(const int* __restrict__ deg,
                                                  const int* __restrict__ locincl,
                                                  const int* __restrict__ bsum,
                                                  int* __restrict__ rowptr,
                                                  int* __restrict__ cursor, int N, int E) {
    const int i = blockIdx.x * 256 + threadIdx.x;
    if (i < N) {
        int excl = bsum[blockIdx.x] + locincl[i] - deg[i];
        rowptr[i] = excl;
        cursor[i] = excl;
    }
    if (i == 0) rowptr[N] = E;
}

__global__ void scatter_kernel(const int* __restrict__ src, const int* __restrict__ dst,
                               int* __restrict__ cursor, int* __restrict__ esrc, int E) {
    int e = blockIdx.x * blockDim.x + threadIdx.x;
    if (e < E) {
        int pos = atomicAdd(&cursor[dst[e]], 1);
        esrc[pos] = src[e];
    }
}

// ---------------- CSR mean-aggregation: fp16 in, fp16 out ----------------
__global__ __launch_bounds__(256) void agg_csr(const fp16_t* __restrict__ h,
                                               const int* __restrict__ rowptr,
                                               const int* __restrict__ esrc,
                                               fp16_t* __restrict__ mean, int N) {
    __shared__ int sl[256];
    const int n = blockIdx.x;
    const int c = threadIdx.x;
    const int r0 = rowptr[n];
    const int r1 = rowptr[n + 1];
    float acc = 0.f;
    for (int base = r0; base < r1; base += 256) {
        int m = min(256, r1 - base);
        if (c < m) sl[c] = esrc[base + c];
        __syncthreads();
        int i = 0;
        for (; i + 4 <= m; i += 4) {
            float a0 = (float)h[(long long)sl[i + 0] * HID + c];
            float a1 = (float)h[(long long)sl[i + 1] * HID + c];
            float a2 = (float)h[(long long)sl[i + 2] * HID + c];
            float a3 = (float)h[(long long)sl[i + 3] * HID + c];
            acc += (a0 + a1) + (a2 + a3);
        }
        for (; i < m; ++i) acc += (float)h[(long long)sl[i] * HID + c];
        __syncthreads();
    }
    float inv = 1.0f / fmaxf((float)(r1 - r0), 1.0f);
    mean[(size_t)n * HID + c] = (fp16_t)(acc * inv);
}

// ---------------- Final linear: out[N,12] = h[N,128] @ W[128,12] + b ----------------
__global__ void lin_final(const float* __restrict__ X, const float* __restrict__ W,
                          const float* __restrict__ b, float* __restrict__ Y, int N) {
    int idx = blockIdx.x * blockDim.x + threadIdx.x;
    if (idx >= N * OUT_DIM) return;
    int row = idx / OUT_DIM;
    int j = idx - row * OUT_DIM;
    float acc = b[j];
#pragma unroll 8
    for (int k = 0; k < 128; ++k)
        acc = fmaf(X[row * 128 + k], W[k * OUT_DIM + j], acc);
    Y[idx] = acc;
}

extern "C" void kernel_launch(void* const* d_in, const int* in_sizes, int n_in,
                              void* d_out, int out_size, void* d_ws, size_t ws_size,
                              hipStream_t stream) {
    const float* x      = (const float*)d_in[0];
    const int*   eidx   = (const int*)d_in[1];
    const float* enc_w1 = (const float*)d_in[2];
    const float* enc_b1 = (const float*)d_in[3];
    const float* enc_w2 = (const float*)d_in[4];
    const float* enc_b2 = (const float*)d_in[5];
    const float* s1_wl  = (const float*)d_in[6];
    const float* s1_bl  = (const float*)d_in[7];
    const float* s1_wr  = (const float*)d_in[8];
    const float* s2_wl  = (const float*)d_in[9];
    const float* s2_bl  = (const float*)d_in[10];
    const float* s2_wr  = (const float*)d_in[11];
    const float* ro_w1  = (const float*)d_in[12];
    const float* ro_b1  = (const float*)d_in[13];
    const float* ro_w2  = (const float*)d_in[14];
    const float* ro_b2  = (const float*)d_in[15];
    float* out = (float*)d_out;

    const int N = N_NODES;
    const int E = N_EDGES;
    const int* src = eidx;
    const int* dst = eidx + E;

    char* ws = (char*)d_ws;
    size_t off = 0;
    auto alloc = [&](size_t bytes) { void* p = ws + off; off += (bytes + 255) & ~255ULL; return p; };
    int* deg     = (int*)alloc((size_t)N * 4);
    int* rowptr  = (int*)alloc((size_t)(N + 1) * 4);
    int* cursor  = (int*)alloc((size_t)N * 4);
    int* esrc    = (int*)alloc((size_t)E * 4);
    int* locincl = (int*)alloc((size_t)N * 4);
    int* bsum    = (int*)alloc((size_t)256 * 4);
    fp16_t* wtE_hi  = (fp16_t*)alloc((size_t)256 * 128 * 2);
    fp16_t* wtE_lo  = (fp16_t*)alloc((size_t)256 * 128 * 2);
    fp16_t* wtS1_hi = (fp16_t*)alloc((size_t)256 * 512 * 2);
    fp16_t* wtS1_lo = (fp16_t*)alloc((size_t)256 * 512 * 2);
    fp16_t* wtS2_hi = (fp16_t*)alloc((size_t)256 * 512 * 2);
    fp16_t* wtS2_lo = (fp16_t*)alloc((size_t)256 * 512 * 2);
    fp16_t* wtR_hi  = (fp16_t*)alloc((size_t)128 * 256 * 2);
    fp16_t* wtR_lo  = (fp16_t*)alloc((size_t)128 * 256 * 2);
    fp16_t* h0   = (fp16_t*)alloc((size_t)N * 128 * 2);
    float* f32buf = (float*)alloc((size_t)N * 128 * 4);
    fp16_t* hA   = (fp16_t*)alloc((size_t)N * HID * 2);
    fp16_t* hB   = (fp16_t*)alloc((size_t)N * HID * 2);
    fp16_t* mbuf = (fp16_t*)alloc((size_t)N * HID * 2);

    const int nb8 = (N + 7) / 8;
    const int gx = (N + 127) / 128;
    const int nbScan = (N + 255) / 256;

    // ---- CSR build ----
    hipMemsetAsync(deg, 0, (size_t)N * 4, stream);
    deg_kernel<<<(E + 255) / 256, 256, 0, stream>>>(dst, deg, E);
    scan_local<<<nbScan, 256, 0, stream>>>(deg, locincl, bsum, N);
    scan_bsum<<<1, 256, 0, stream>>>(bsum, nbScan);
    scan_final<<<nbScan, 256, 0, stream>>>(deg, locincl, bsum, rowptr, cursor, N, E);
    scatter_kernel<<<(E + 255) / 256, 256, 0, stream>>>(src, dst, cursor, esrc, E);

    // ---- weight transpose + split ----
    wtrans<<<(256 * 128 + 255) / 256, 256, 0, stream>>>(enc_w2, nullptr, 128, 128, 256, wtE_hi, wtE_lo);
    wtrans<<<(256 * 512 + 255) / 256, 256, 0, stream>>>(s1_wl, s1_wr, 256, 512, 256, wtS1_hi, wtS1_lo);
    wtrans<<<(256 * 512 + 255) / 256, 256, 0, stream>>>(s2_wl, s2_wr, 256, 512, 256, wtS2_hi, wtS2_lo);
    wtrans<<<(128 * 256 + 255) / 256, 256, 0, stream>>>(ro_w1, nullptr, 256, 256, 128, wtR_hi, wtR_lo);

    // ---- encoder ----
    lin_enc1<IN_DIM, 128, 8><<<nb8, 128, 0, stream>>>(x, enc_w1, enc_b1, h0, N);
    gemm_mfma<128, 0, 256, false, true, true><<<dim3(gx, 1), 512, 0, stream>>>(
        h0, nullptr, wtE_hi, wtE_lo, enc_b2, nullptr, hA, N, 256);

    // ---- SAGE 1 ----
    agg_csr<<<N, 256, 0, stream>>>(hA, rowptr, esrc, mbuf, N);
    gemm_mfma<512, 1, 256, false, true, true><<<dim3(gx, 1), 512, 0, stream>>>(
        mbuf, hA, wtS1_hi, wtS1_lo, s1_bl, nullptr, hB, N, 256);

    // ---- SAGE 2 ----
    agg_csr<<<N, 256, 0, stream>>>(hB, rowptr, esrc, mbuf, N);
    gemm_mfma<512, 1, 256, false, true, true><<<dim3(gx, 1), 512, 0, stream>>>(
        mbuf, hB, wtS2_hi, wtS2_lo, s2_bl, nullptr, hA, N, 256);

    // ---- readout ----
    gemm_mfma<256, 0, 128, true, false, true><<<dim3(gx, 1), 256, 0, stream>>>(
        hA, nullptr, wtR_hi, wtR_lo, ro_b1, f32buf, nullptr, N, 128);
    lin_final<<<(N * OUT_DIM + 255) / 256, 256, 0, stream>>>(f32buf, ro_w2, ro_b2, out, N);
}

// Round 9
// 295.209 us; speedup vs baseline: 5.4292x; 1.1504x over previous
//
#include <hip/hip_runtime.h>
#include <hip/hip_bf16.h>

#define N_NODES 50000
#define N_EDGES 400000
#define IN_DIM 24
#define HID 256
#define OUT_DIM 12

typedef _Float16 fp16_t;
typedef __attribute__((ext_vector_type(8))) _Float16 half8;
typedef __attribute__((ext_vector_type(4))) float f32x4;

// async global->LDS, 16 bytes per lane (dest must be linear: base + lane*16 per wave)
__device__ __forceinline__ void gload_lds16(const void* g, void* l) {
    typedef __attribute__((address_space(3))) unsigned int u32_lds;
    typedef const __attribute__((address_space(1))) unsigned int u32_glb;
    __builtin_amdgcn_global_load_lds((u32_glb*)(unsigned long long)g,
                                     (u32_lds*)(unsigned int)(unsigned long long)l,
                                     16, 0, 0);
}

// ---------------- encoder layer 1 (K=24, f32 compute, fp16 out) ----------------
template<int K, int M, int ROWS>
__global__ __launch_bounds__(M) void lin_enc1(const float* __restrict__ X,
                                              const float* __restrict__ W,
                                              const float* __restrict__ b,
                                              fp16_t* __restrict__ Y, int N) {
    __shared__ float xs[ROWS][K];
    const int row0 = blockIdx.x * ROWS;
    const int tid = threadIdx.x;
    for (int i = tid; i < ROWS * K; i += M) {
        int r = i / K, k = i - r * K;
        int gr = row0 + r;
        xs[r][k] = (gr < N) ? X[(long long)gr * K + k] : 0.f;
    }
    __syncthreads();
    const int j = tid;
    float acc[ROWS];
    float bj = b[j];
#pragma unroll
    for (int r = 0; r < ROWS; ++r) acc[r] = bj;
    for (int k = 0; k < K; ++k) {
        float w = W[k * M + j];
#pragma unroll
        for (int r = 0; r < ROWS; ++r) acc[r] = fmaf(xs[r][k], w, acc[r]);
    }
#pragma unroll
    for (int r = 0; r < ROWS; ++r) {
        int gr = row0 + r;
        if (gr < N) {
            float v = fmaxf(acc[r], 0.f);
            Y[(size_t)gr * M + j] = (fp16_t)v;
        }
    }
}

// ---------------- weight transpose + fp16 hi/lo split: Wt[j][k] = W[k][j] ----------------
__global__ void wtrans(const float* __restrict__ W1, const float* __restrict__ W2,
                       int K1, int K, int M,
                       fp16_t* __restrict__ Whi, fp16_t* __restrict__ Wlo) {
    int idx = blockIdx.x * blockDim.x + threadIdx.x;
    if (idx >= M * K) return;
    int j = idx / K, k = idx - j * K;
    float v = (k < K1) ? W1[(size_t)k * M + j] : W2[(size_t)(k - K1) * M + j];
    fp16_t h = (fp16_t)v;
    Whi[idx] = h;
    Wlo[idx] = (fp16_t)(v - (float)h);
}

// ---------------- MFMA fp16 GEMM: Y = relu?(A @ (Whi+Wlo)^T + b) ----------------
// Block tile 128 x BN, BK=32. Waves: BN*2/64, wave tile 64x64 (4x4 frags 16x16x32).
// MODE 0: A rows from A [N][K]
// MODE 1: k<HID from A [N][HID] (mean), else A2 [N][HID] (h)
template<int K, int MODE, int BN, bool WF32, bool WH16, bool RELU>
__global__ __launch_bounds__(BN * 2, 4) void gemm_mfma(
    const fp16_t* __restrict__ A, const fp16_t* __restrict__ A2,
    const fp16_t* __restrict__ Whi, const fp16_t* __restrict__ Wlo,
    const float* __restrict__ bias,
    float* __restrict__ Yf, fp16_t* __restrict__ Yh,
    int N, int M) {
    constexpr int NT = BN * 2;          // threads
    constexpr int NWC = BN / 64;        // wave columns
    __shared__ __align__(16) fp16_t ldsA[128 * 32];
    __shared__ __align__(16) fp16_t ldsBh[BN * 32];
    __shared__ __align__(16) fp16_t ldsBl[BN * 32];
    const int tid = threadIdx.x;
    const int r0 = blockIdx.x * 128;
    const int j0 = blockIdx.y * BN;
    const int w = tid >> 6, lane = tid & 63;
    const int wr = w / NWC, wc = w % NWC;
    const int lrow = lane & 15, lg = lane >> 4;

    f32x4 acc[4][4] = {};

    for (int kc = 0; kc < K; kc += 32) {
        __syncthreads();
        // ---- stage A tile (128 x 32) : 512 x 16B chunks ----
        const fp16_t* pa;
        int ka, KA;
        if (MODE == 1) {
            KA = HID;
            if (kc >= HID) { pa = A2; ka = kc - HID; }
            else           { pa = A;  ka = kc; }
        } else {
            KA = K; pa = A; ka = kc;
        }
#pragma unroll
        for (int c = tid; c < 512; c += NT) {
            int row = c >> 2, cg = c & 3;
            int gr = r0 + row; if (gr > N - 1) gr = N - 1;
            size_t go = (size_t)gr * KA + ka + cg * 8;
            gload_lds16(pa + go, (char*)ldsA + (size_t)c * 16);
        }
        // ---- stage B tiles (BN x 32, hi+lo) : BN*4 x 16B chunks each ----
#pragma unroll
        for (int c = tid; c < BN * 4; c += NT) {
            int wrow = c >> 2, cg = c & 3;
            size_t go = (size_t)(j0 + wrow) * K + kc + cg * 8;
            gload_lds16(Whi + go, (char*)ldsBh + (size_t)c * 16);
            gload_lds16(Wlo + go, (char*)ldsBl + (size_t)c * 16);
        }
        __syncthreads();

        half8 a[4], bh[4], bl[4];
#pragma unroll
        for (int f = 0; f < 4; ++f) {
            int ar = wr * 64 + f * 16 + lrow;
            a[f] = *(const half8*)&ldsA[ar * 32 + lg * 8];
            int br = wc * 64 + f * 16 + lrow;
            bh[f] = *(const half8*)&ldsBh[br * 32 + lg * 8];
            bl[f] = *(const half8*)&ldsBl[br * 32 + lg * 8];
        }
#pragma unroll
        for (int fi = 0; fi < 4; ++fi)
#pragma unroll
            for (int fj = 0; fj < 4; ++fj) {
                acc[fi][fj] = __builtin_amdgcn_mfma_f32_16x16x32_f16(a[fi], bh[fj], acc[fi][fj], 0, 0, 0);
                acc[fi][fj] = __builtin_amdgcn_mfma_f32_16x16x32_f16(a[fi], bl[fj], acc[fi][fj], 0, 0, 0);
            }
    }

    // ---- epilogue: C/D layout col=lane&15, row=(lane>>4)*4+reg ----
#pragma unroll
    for (int fj = 0; fj < 4; ++fj) {
        int ocol = j0 + wc * 64 + fj * 16 + lrow;
        float bv = bias[ocol];
#pragma unroll
        for (int fi = 0; fi < 4; ++fi) {
#pragma unroll
            for (int r = 0; r < 4; ++r) {
                int orow = r0 + wr * 64 + fi * 16 + lg * 4 + r;
                if (orow < N) {
                    float v = acc[fi][fj][r] + bv;
                    if (RELU) v = fmaxf(v, 0.f);
                    size_t o = (size_t)orow * M + ocol;
                    if (WF32) Yf[o] = v;
                    if (WH16) Yh[o] = (fp16_t)v;
                }
            }
        }
    }
}

// ---------------- CSR build ----------------
__global__ void deg_kernel(const int* __restrict__ dst, int* __restrict__ deg, int E) {
    int e = blockIdx.x * blockDim.x + threadIdx.x;
    if (e < E) atomicAdd(&deg[dst[e]], 1);
}

// Stage 1: per-block inclusive scan (256 elems/block) + block total
__global__ __launch_bounds__(256) void scan_local(const int* __restrict__ deg,
                                                  int* __restrict__ locincl,
                                                  int* __restrict__ bsum, int N) {
    const int t = threadIdx.x;
    const int i = blockIdx.x * 256 + t;
    int v = (i < N) ? deg[i] : 0;
    const int lane = t & 63;
    int x = v;
#pragma unroll
    for (int off = 1; off < 64; off <<= 1) {
        int y = __shfl_up(x, off, 64);
        if (lane >= off) x += y;
    }
    __shared__ int wsum[4];
    if (lane == 63) wsum[t >> 6] = x;
    __syncthreads();
    const int wid = t >> 6;
    int add = 0;
    for (int wI = 0; wI < wid; ++wI) add += wsum[wI];
    x += add;
    if (i < N) locincl[i] = x;
    if (t == 255) bsum[blockIdx.x] = x;
}

// Stage 2: exclusive scan of block sums (B <= 256), single block
__global__ __launch_bounds__(256) void scan_bsum(int* __restrict__ bsum, int B) {
    const int t = threadIdx.x;
    int v = (t < B) ? bsum[t] : 0;
    const int lane = t & 63;
    int x = v;
#pragma unroll
    for (int off = 1; off < 64; off <<= 1) {
        int y = __shfl_up(x, off, 64);
        if (lane >= off) x += y;
    }
    __shared__ int wsum[4];
    if (lane == 63) wsum[t >> 6] = x;
    __syncthreads();
    const int wid = t >> 6;
    int add = 0;
    for (int wI = 0; wI < wid; ++wI) add += wsum[wI];
    x += add;
    if (t < B) bsum[t] = x - v;   // exclusive
}

// Stage 3: recombine -> exclusive rowptr + cursor
__global__ __launch_bounds__(256) void scan_final(const int* __restrict__ deg,
                                                  const int* __restrict__ locincl,
                                                  const int* __restrict__ bsum,
                                                  int* __restrict__ rowptr,
                                                  int* __restrict__ cursor, int N, int E) {
    const int i = blockIdx.x * 256 + threadIdx.x;
    if (i < N) {
        int excl = bsum[blockIdx.x] + locincl[i] - deg[i];
        rowptr[i] = excl;
        cursor[i] = excl;
    }
    if (i == 0) rowptr[N] = E;
}

__global__ void scatter_kernel(const int* __restrict__ src, const int* __restrict__ dst,
                               int* __restrict__ cursor, int* __restrict__ esrc, int E) {
    int e = blockIdx.x * blockDim.x + threadIdx.x;
    if (e < E) {
        int pos = atomicAdd(&cursor[dst[e]], 1);
        esrc[pos] = src[e];
    }
}

// ---------------- CSR mean-aggregation: wave-per-node, 16B/lane gathers ----------------
// Lanes 0-31 process even edges, lanes 32-63 odd edges; each lane owns 8 channels.
__global__ __launch_bounds__(256) void agg_csr(const fp16_t* __restrict__ h,
                                               const int* __restrict__ rowptr,
                                               const int* __restrict__ esrc,
                                               fp16_t* __restrict__ mean, int N) {
    const int n = blockIdx.x * 4 + (threadIdx.x >> 6);
    if (n >= N) return;
    const int lane = threadIdx.x & 63;
    const int half = lane >> 5;         // 0 or 1
    const int l32 = lane & 31;          // channel group 0..31 (8 ch each)
    const int r0 = rowptr[n];
    const int r1 = rowptr[n + 1];
    const int deg = r1 - r0;

    float acc[8];
#pragma unroll
    for (int j = 0; j < 8; ++j) acc[j] = 0.f;

    for (int e = r0 + half; e < r1; e += 2) {
        int s = esrc[e];
        half8 v = *(const half8*)&h[(size_t)s * HID + l32 * 8];
#pragma unroll
        for (int j = 0; j < 8; ++j) acc[j] += (float)v[j];
    }
    // combine the two half-waves (lane ^ 32 partner holds the other edge parity)
#pragma unroll
    for (int j = 0; j < 8; ++j) acc[j] += __shfl(acc[j], lane ^ 32, 64);

    if (half == 0) {
        float inv = 1.0f / fmaxf((float)deg, 1.0f);
        half8 o;
#pragma unroll
        for (int j = 0; j < 8; ++j) o[j] = (fp16_t)(acc[j] * inv);
        *(half8*)&mean[(size_t)n * HID + l32 * 8] = o;
    }
}

// ---------------- Final linear: out[N,12] = h[N,128] @ W[128,12] + b ----------------
__global__ void lin_final(const float* __restrict__ X, const float* __restrict__ W,
                          const float* __restrict__ b, float* __restrict__ Y, int N) {
    int idx = blockIdx.x * blockDim.x + threadIdx.x;
    if (idx >= N * OUT_DIM) return;
    int row = idx / OUT_DIM;
    int j = idx - row * OUT_DIM;
    float acc = b[j];
#pragma unroll 8
    for (int k = 0; k < 128; ++k)
        acc = fmaf(X[row * 128 + k], W[k * OUT_DIM + j], acc);
    Y[idx] = acc;
}

extern "C" void kernel_launch(void* const* d_in, const int* in_sizes, int n_in,
                              void* d_out, int out_size, void* d_ws, size_t ws_size,
                              hipStream_t stream) {
    const float* x      = (const float*)d_in[0];
    const int*   eidx   = (const int*)d_in[1];
    const float* enc_w1 = (const float*)d_in[2];
    const float* enc_b1 = (const float*)d_in[3];
    const float* enc_w2 = (const float*)d_in[4];
    const float* enc_b2 = (const float*)d_in[5];
    const float* s1_wl  = (const float*)d_in[6];
    const float* s1_bl  = (const float*)d_in[7];
    const float* s1_wr  = (const float*)d_in[8];
    const float* s2_wl  = (const float*)d_in[9];
    const float* s2_bl  = (const float*)d_in[10];
    const float* s2_wr  = (const float*)d_in[11];
    const float* ro_w1  = (const float*)d_in[12];
    const float* ro_b1  = (const float*)d_in[13];
    const float* ro_w2  = (const float*)d_in[14];
    const float* ro_b2  = (const float*)d_in[15];
    float* out = (float*)d_out;

    const int N = N_NODES;
    const int E = N_EDGES;
    const int* src = eidx;
    const int* dst = eidx + E;

    char* ws = (char*)d_ws;
    size_t off = 0;
    auto alloc = [&](size_t bytes) { void* p = ws + off; off += (bytes + 255) & ~255ULL; return p; };
    int* deg     = (int*)alloc((size_t)N * 4);
    int* rowptr  = (int*)alloc((size_t)(N + 1) * 4);
    int* cursor  = (int*)alloc((size_t)N * 4);
    int* esrc    = (int*)alloc((size_t)E * 4);
    int* locincl = (int*)alloc((size_t)N * 4);
    int* bsum    = (int*)alloc((size_t)256 * 4);
    fp16_t* wtE_hi  = (fp16_t*)alloc((size_t)256 * 128 * 2);
    fp16_t* wtE_lo  = (fp16_t*)alloc((size_t)256 * 128 * 2);
    fp16_t* wtS1_hi = (fp16_t*)alloc((size_t)256 * 512 * 2);
    fp16_t* wtS1_lo = (fp16_t*)alloc((size_t)256 * 512 * 2);
    fp16_t* wtS2_hi = (fp16_t*)alloc((size_t)256 * 512 * 2);
    fp16_t* wtS2_lo = (fp16_t*)alloc((size_t)256 * 512 * 2);
    fp16_t* wtR_hi  = (fp16_t*)alloc((size_t)128 * 256 * 2);
    fp16_t* wtR_lo  = (fp16_t*)alloc((size_t)128 * 256 * 2);
    fp16_t* h0   = (fp16_t*)alloc((size_t)N * 128 * 2);
    float* f32buf = (float*)alloc((size_t)N * 128 * 4);
    fp16_t* hA   = (fp16_t*)alloc((size_t)N * HID * 2);
    fp16_t* hB   = (fp16_t*)alloc((size_t)N * HID * 2);
    fp16_t* mbuf = (fp16_t*)alloc((size_t)N * HID * 2);

    const int nb8 = (N + 7) / 8;
    const int gx = (N + 127) / 128;
    const int nbScan = (N + 255) / 256;
    const int nbAgg = (N + 3) / 4;

    // ---- CSR build ----
    hipMemsetAsync(deg, 0, (size_t)N * 4, stream);
    deg_kernel<<<(E + 255) / 256, 256, 0, stream>>>(dst, deg, E);
    scan_local<<<nbScan, 256, 0, stream>>>(deg, locincl, bsum, N);
    scan_bsum<<<1, 256, 0, stream>>>(bsum, nbScan);
    scan_final<<<nbScan, 256, 0, stream>>>(deg, locincl, bsum, rowptr, cursor, N, E);
    scatter_kernel<<<(E + 255) / 256, 256, 0, stream>>>(src, dst, cursor, esrc, E);

    // ---- weight transpose + split ----
    wtrans<<<(256 * 128 + 255) / 256, 256, 0, stream>>>(enc_w2, nullptr, 128, 128, 256, wtE_hi, wtE_lo);
    wtrans<<<(256 * 512 + 255) / 256, 256, 0, stream>>>(s1_wl, s1_wr, 256, 512, 256, wtS1_hi, wtS1_lo);
    wtrans<<<(256 * 512 + 255) / 256, 256, 0, stream>>>(s2_wl, s2_wr, 256, 512, 256, wtS2_hi, wtS2_lo);
    wtrans<<<(128 * 256 + 255) / 256, 256, 0, stream>>>(ro_w1, nullptr, 256, 256, 128, wtR_hi, wtR_lo);

    // ---- encoder ----
    lin_enc1<IN_DIM, 128, 8><<<nb8, 128, 0, stream>>>(x, enc_w1, enc_b1, h0, N);
    gemm_mfma<128, 0, 256, false, true, true><<<dim3(gx, 1), 512, 0, stream>>>(
        h0, nullptr, wtE_hi, wtE_lo, enc_b2, nullptr, hA, N, 256);

    // ---- SAGE 1 ----
    agg_csr<<<nbAgg, 256, 0, stream>>>(hA, rowptr, esrc, mbuf, N);
    gemm_mfma<512, 1, 256, false, true, true><<<dim3(gx, 1), 512, 0, stream>>>(
        mbuf, hA, wtS1_hi, wtS1_lo, s1_bl, nullptr, hB, N, 256);

    // ---- SAGE 2 ----
    agg_csr<<<nbAgg, 256, 0, stream>>>(hB, rowptr, esrc, mbuf, N);
    gemm_mfma<512, 1, 256, false, true, true><<<dim3(gx, 1), 512, 0, stream>>>(
        mbuf, hB, wtS2_hi, wtS2_lo, s2_bl, nullptr, hA, N, 256);

    // ---- readout ----
    gemm_mfma<256, 0, 128, true, false, true><<<dim3(gx, 1), 256, 0, stream>>>(
        hA, nullptr, wtR_hi, wtR_lo, ro_b1, f32buf, nullptr, N, 128);
    lin_final<<<(N * OUT_DIM + 255) / 256, 256, 0, stream>>>(f32buf, ro_w2, ro_b2, out, N);
}